// Round 1
// baseline (2930.150 us; speedup 1.0000x reference)
//
#include <hip/hip_runtime.h>
#include <math.h>

#define N_NODES 100000
#define F_IN    128
#define HID     64
#define N_CLS   40

// ---------------------------------------------------------------------------
// gemm1: y1 = x @ W1_l, z1 = x @ W1_r          [N,128] x [128,64] -> [N,64]
// One wave (64 lanes) per node; lane j computes output column j.
// x loads are wave-uniform (broadcast), W loads are coalesced across lanes.
// ---------------------------------------------------------------------------
__global__ void gemm1_kernel(const float* __restrict__ x,
                             const float* __restrict__ Wl,
                             const float* __restrict__ Wr,
                             float* __restrict__ y1,
                             float* __restrict__ z1) {
    int gid = blockIdx.x * blockDim.x + threadIdx.x;
    int n = gid >> 6;
    int j = gid & 63;
    if (n >= N_NODES) return;
    const float* xr = x + (size_t)n * F_IN;
    float accl = 0.f, accr = 0.f;
#pragma unroll 8
    for (int k = 0; k < F_IN; ++k) {
        float xv = xr[k];
        accl = fmaf(xv, Wl[k * HID + j], accl);
        accr = fmaf(xv, Wr[k * HID + j], accr);
    }
    y1[(size_t)n * HID + j] = accl;
    z1[(size_t)n * HID + j] = accr;
}

// ---------------------------------------------------------------------------
// scatter1: s1[dst] += y1[src] (64 floats per edge as 16 float4 chunks),
// fused degree count on chunk 0.
// ---------------------------------------------------------------------------
__global__ void scatter1_kernel(const int* __restrict__ ei, int E,
                                const float* __restrict__ y1,
                                float* __restrict__ s1,
                                float* __restrict__ cnt) {
    int gid = blockIdx.x * blockDim.x + threadIdx.x;
    int e = gid >> 4;      // edge
    int c = gid & 15;      // float4 chunk within the 64-float row
    if (e >= E) return;
    int src = ei[e];
    int dst = ei[E + e];
    const float4 v = *(const float4*)(y1 + (size_t)src * HID + c * 4);
    float* d = s1 + (size_t)dst * HID + c * 4;
    unsafeAtomicAdd(d + 0, v.x);
    unsafeAtomicAdd(d + 1, v.y);
    unsafeAtomicAdd(d + 2, v.z);
    unsafeAtomicAdd(d + 3, v.w);
    if (c == 0) unsafeAtomicAdd(cnt + dst, 1.0f);
}

// ---------------------------------------------------------------------------
// epi1: h = relu(s1 / max(cnt,1) + b1 + z1)
// ---------------------------------------------------------------------------
__global__ void epi1_kernel(const float* __restrict__ s1,
                            const float* __restrict__ z1,
                            const float* __restrict__ b1,
                            const float* __restrict__ cnt,
                            float* __restrict__ h) {
    int gid = blockIdx.x * blockDim.x + threadIdx.x;
    int n = gid >> 6;
    int j = gid & 63;
    if (n >= N_NODES) return;
    float inv = 1.0f / fmaxf(cnt[n], 1.0f);
    float v = fmaf(s1[gid], inv, b1[j] + z1[gid]);
    h[gid] = fmaxf(v, 0.0f);
}

// ---------------------------------------------------------------------------
// gemm2: y2 = h @ W2_l, z2 = h @ W2_r          [N,64] x [64,40] -> [N,40]
// One wave per node; lanes 0..39 active for output, all lanes share h row.
// ---------------------------------------------------------------------------
__global__ void gemm2_kernel(const float* __restrict__ h,
                             const float* __restrict__ Wl,
                             const float* __restrict__ Wr,
                             float* __restrict__ y2,
                             float* __restrict__ z2) {
    int gid = blockIdx.x * blockDim.x + threadIdx.x;
    int n = gid >> 6;
    int j = gid & 63;
    if (n >= N_NODES) return;
    if (j >= N_CLS) return;
    const float* hr = h + (size_t)n * HID;
    float accl = 0.f, accr = 0.f;
#pragma unroll 8
    for (int k = 0; k < HID; ++k) {
        float hv = hr[k];
        accl = fmaf(hv, Wl[k * N_CLS + j], accl);
        accr = fmaf(hv, Wr[k * N_CLS + j], accr);
    }
    y2[(size_t)n * N_CLS + j] = accl;
    z2[(size_t)n * N_CLS + j] = accr;
}

// ---------------------------------------------------------------------------
// scatter2: s2[dst] += y2[src] (40 floats per edge as 10 float4 chunks)
// ---------------------------------------------------------------------------
__global__ void scatter2_kernel(const int* __restrict__ ei, int E,
                                const float* __restrict__ y2,
                                float* __restrict__ s2) {
    unsigned gid = blockIdx.x * blockDim.x + threadIdx.x;
    unsigned e = gid / 10u;
    unsigned c = gid - e * 10u;
    if (e >= (unsigned)E) return;
    int src = ei[e];
    int dst = ei[E + e];
    const float4 v = *(const float4*)(y2 + (size_t)src * N_CLS + c * 4);
    float* d = s2 + (size_t)dst * N_CLS + c * 4;
    unsafeAtomicAdd(d + 0, v.x);
    unsafeAtomicAdd(d + 1, v.y);
    unsafeAtomicAdd(d + 2, v.z);
    unsafeAtomicAdd(d + 3, v.w);
}

// ---------------------------------------------------------------------------
// softmax: logits = s2/max(cnt,1) + b2 + z2 ; out = log_softmax(logits)
// One wave per node, lane j = class (lanes 40..63 idle in reductions via
// -inf / 0 identities).
// ---------------------------------------------------------------------------
__global__ void softmax_kernel(const float* __restrict__ s2,
                               const float* __restrict__ z2,
                               const float* __restrict__ b2,
                               const float* __restrict__ cnt,
                               float* __restrict__ out) {
    int gid = blockIdx.x * blockDim.x + threadIdx.x;
    int n = gid >> 6;
    int j = gid & 63;
    if (n >= N_NODES) return;
    float val = -INFINITY;
    if (j < N_CLS) {
        float inv = 1.0f / fmaxf(cnt[n], 1.0f);
        val = fmaf(s2[(size_t)n * N_CLS + j], inv,
                   b2[j] + z2[(size_t)n * N_CLS + j]);
    }
    float m = val;
#pragma unroll
    for (int off = 32; off > 0; off >>= 1)
        m = fmaxf(m, __shfl_xor(m, off, 64));
    float ex = (j < N_CLS) ? expf(val - m) : 0.0f;
    float s = ex;
#pragma unroll
    for (int off = 32; off > 0; off >>= 1)
        s += __shfl_xor(s, off, 64);
    if (j < N_CLS) out[(size_t)n * N_CLS + j] = val - m - logf(s);
}

extern "C" void kernel_launch(void* const* d_in, const int* in_sizes, int n_in,
                              void* d_out, int out_size, void* d_ws, size_t ws_size,
                              hipStream_t stream) {
    const float* x   = (const float*)d_in[0];
    const int*   ei  = (const int*)d_in[1];
    const float* W1l = (const float*)d_in[2];
    const float* b1  = (const float*)d_in[3];
    const float* W1r = (const float*)d_in[4];
    const float* W2l = (const float*)d_in[5];
    const float* b2  = (const float*)d_in[6];
    const float* W2r = (const float*)d_in[7];
    float* out = (float*)d_out;
    const int E = in_sizes[1] / 2;

    // Workspace layout (floats). cnt/s1/s2 contiguous -> one memset.
    float* ws  = (float*)d_ws;
    float* cnt = ws;                                  // N
    float* s1  = cnt + N_NODES;                       // N*64   (zeroed)
    float* s2  = s1 + (size_t)N_NODES * HID;          // N*40   (zeroed)
    float* y1  = s2 + (size_t)N_NODES * N_CLS;        // N*64   (later: h)
    float* z1  = y1 + (size_t)N_NODES * HID;          // N*64   (later: y2)
    // z2 reuses s1's buffer after epi1 consumed s1.

    hipMemsetAsync(ws, 0, (size_t)N_NODES * (1 + HID + N_CLS) * sizeof(float),
                   stream);

    const int B = 256;
    int t_nodes64 = N_NODES * 64;

    gemm1_kernel<<<(t_nodes64 + B - 1) / B, B, 0, stream>>>(x, W1l, W1r, y1, z1);

    int t_sc1 = E * 16;
    scatter1_kernel<<<(t_sc1 + B - 1) / B, B, 0, stream>>>(ei, E, y1, s1, cnt);

    // h overwrites y1 (y1 dead after scatter1)
    epi1_kernel<<<(t_nodes64 + B - 1) / B, B, 0, stream>>>(s1, z1, b1, cnt, y1);

    // y2 -> z1's buffer, z2 -> s1's buffer (both dead after epi1)
    float* y2 = z1;
    float* z2 = s1;
    gemm2_kernel<<<(t_nodes64 + B - 1) / B, B, 0, stream>>>(y1, W2l, W2r, y2, z2);

    int t_sc2 = E * 10;
    scatter2_kernel<<<(t_sc2 + B - 1) / B, B, 0, stream>>>(ei, E, y2, s2);

    softmax_kernel<<<(t_nodes64 + B - 1) / B, B, 0, stream>>>(s2, z2, b2, cnt, out);
}

// Round 2
// 1141.044 us; speedup vs baseline: 2.5680x; 2.5680x over previous
//
#include <hip/hip_runtime.h>
#include <math.h>

#define N_NODES 100000
#define F_IN    128
#define HID     64
#define N_CLS   40
#define SCAN_T  1024
#define SCAN_CH ((N_NODES + SCAN_T - 1) / SCAN_T)   // 98

// ---------------------------------------------------------------------------
// CSR build step 1: in-degree histogram
// ---------------------------------------------------------------------------
__global__ void hist_kernel(const int* __restrict__ ei, int E,
                            int* __restrict__ deg) {
    int e = blockIdx.x * blockDim.x + threadIdx.x;
    if (e < E) atomicAdd(&deg[ei[E + e]], 1);
}

// ---------------------------------------------------------------------------
// CSR build step 2: exclusive prefix scan (single workgroup, 1024 threads,
// each owns a contiguous chunk of 98 nodes). Writes rowptr[N+1] and a
// working copy wofs[] for the fill pass.
// ---------------------------------------------------------------------------
__global__ void scan_kernel(const int* __restrict__ deg,
                            int* __restrict__ rowptr,
                            int* __restrict__ wofs) {
    __shared__ int ssum[SCAN_T];
    int t = threadIdx.x;
    int lo = t * SCAN_CH;
    int hi = min(lo + SCAN_CH, N_NODES);
    int s = 0;
    for (int i = lo; i < hi; ++i) s += deg[i];
    ssum[t] = s;
    __syncthreads();
    // Hillis-Steele inclusive scan over the 1024 chunk sums
    for (int off = 1; off < SCAN_T; off <<= 1) {
        int v = (t >= off) ? ssum[t - off] : 0;
        __syncthreads();
        ssum[t] += v;
        __syncthreads();
    }
    int run = (t > 0) ? ssum[t - 1] : 0;   // exclusive base for this chunk
    for (int i = lo; i < hi; ++i) {
        rowptr[i] = run;
        wofs[i] = run;
        run += deg[i];
    }
    if (t == 0) rowptr[N_NODES] = ssum[SCAN_T - 1];
}

// ---------------------------------------------------------------------------
// CSR build step 3: bucket fill (src ids grouped by dst)
// ---------------------------------------------------------------------------
__global__ void fill_kernel(const int* __restrict__ ei, int E,
                            int* __restrict__ wofs,
                            int* __restrict__ csr) {
    int e = blockIdx.x * blockDim.x + threadIdx.x;
    if (e >= E) return;
    int src = ei[e];
    int dst = ei[E + e];
    int p = atomicAdd(&wofs[dst], 1);
    csr[p] = src;
}

// ---------------------------------------------------------------------------
// gemm1: y1 = x @ W1_l, z1 = x @ W1_r     [N,128]x[128,64] -> [N,64]
// One wave per node; lane j = output column. float4 x loads (wave-uniform).
// ---------------------------------------------------------------------------
__global__ void gemm1_kernel(const float* __restrict__ x,
                             const float* __restrict__ Wl,
                             const float* __restrict__ Wr,
                             float* __restrict__ y1,
                             float* __restrict__ z1) {
    int gid = blockIdx.x * blockDim.x + threadIdx.x;
    int n = gid >> 6;
    int j = gid & 63;
    if (n >= N_NODES) return;
    const float4* xr = (const float4*)(x + (size_t)n * F_IN);
    float accl = 0.f, accr = 0.f;
#pragma unroll 4
    for (int k4 = 0; k4 < F_IN / 4; ++k4) {
        float4 xv = xr[k4];
        int k = k4 * 4;
        accl = fmaf(xv.x, Wl[(k + 0) * HID + j], accl);
        accl = fmaf(xv.y, Wl[(k + 1) * HID + j], accl);
        accl = fmaf(xv.z, Wl[(k + 2) * HID + j], accl);
        accl = fmaf(xv.w, Wl[(k + 3) * HID + j], accl);
        accr = fmaf(xv.x, Wr[(k + 0) * HID + j], accr);
        accr = fmaf(xv.y, Wr[(k + 1) * HID + j], accr);
        accr = fmaf(xv.z, Wr[(k + 2) * HID + j], accr);
        accr = fmaf(xv.w, Wr[(k + 3) * HID + j], accr);
    }
    y1[(size_t)n * HID + j] = accl;
    z1[(size_t)n * HID + j] = accr;
}

// ---------------------------------------------------------------------------
// agg1 (+ fused epi): h = relu(mean_{src in N(n)} y1[src] + b1 + z1[n])
// One wave per dst node; lane j accumulates column j in a register.
// ---------------------------------------------------------------------------
__global__ void agg1_kernel(const int* __restrict__ rowptr,
                            const int* __restrict__ csr,
                            const float* __restrict__ y1,
                            const float* __restrict__ z1,
                            const float* __restrict__ b1,
                            float* __restrict__ h) {
    int gid = blockIdx.x * blockDim.x + threadIdx.x;
    int n = gid >> 6;
    int j = gid & 63;
    if (n >= N_NODES) return;
    int beg = rowptr[n], end = rowptr[n + 1];
    float acc = 0.f;
    int i = beg;
    for (; i + 1 < end; i += 2) {
        int s0 = csr[i], s1 = csr[i + 1];
        float v0 = y1[(size_t)s0 * HID + j];
        float v1 = y1[(size_t)s1 * HID + j];
        acc += v0 + v1;
    }
    if (i < end) acc += y1[(size_t)csr[i] * HID + j];
    float inv = 1.0f / fmaxf((float)(end - beg), 1.0f);
    float v = fmaf(acc, inv, b1[j] + z1[gid]);
    h[gid] = fmaxf(v, 0.0f);
}

// ---------------------------------------------------------------------------
// gemm2: y2 = h @ W2_l, z2 = h @ W2_r     [N,64]x[64,40] -> [N,40]
// ---------------------------------------------------------------------------
__global__ void gemm2_kernel(const float* __restrict__ h,
                             const float* __restrict__ Wl,
                             const float* __restrict__ Wr,
                             float* __restrict__ y2,
                             float* __restrict__ z2) {
    int gid = blockIdx.x * blockDim.x + threadIdx.x;
    int n = gid >> 6;
    int j = gid & 63;
    if (n >= N_NODES) return;
    if (j >= N_CLS) return;
    const float4* hr = (const float4*)(h + (size_t)n * HID);
    float accl = 0.f, accr = 0.f;
#pragma unroll 4
    for (int k4 = 0; k4 < HID / 4; ++k4) {
        float4 hv = hr[k4];
        int k = k4 * 4;
        accl = fmaf(hv.x, Wl[(k + 0) * N_CLS + j], accl);
        accl = fmaf(hv.y, Wl[(k + 1) * N_CLS + j], accl);
        accl = fmaf(hv.z, Wl[(k + 2) * N_CLS + j], accl);
        accl = fmaf(hv.w, Wl[(k + 3) * N_CLS + j], accl);
        accr = fmaf(hv.x, Wr[(k + 0) * N_CLS + j], accr);
        accr = fmaf(hv.y, Wr[(k + 1) * N_CLS + j], accr);
        accr = fmaf(hv.z, Wr[(k + 2) * N_CLS + j], accr);
        accr = fmaf(hv.w, Wr[(k + 3) * N_CLS + j], accr);
    }
    y2[(size_t)n * N_CLS + j] = accl;
    z2[(size_t)n * N_CLS + j] = accr;
}

// ---------------------------------------------------------------------------
// agg2 + log_softmax fused. One wave per dst node; lanes 0..39 = classes.
// All 64 lanes run the edge loop (index clamped) so csr broadcasts stay
// wave-uniform; lanes >= 40 contribute identities to the reductions.
// ---------------------------------------------------------------------------
__global__ void agg2_kernel(const int* __restrict__ rowptr,
                            const int* __restrict__ csr,
                            const float* __restrict__ y2,
                            const float* __restrict__ z2,
                            const float* __restrict__ b2,
                            float* __restrict__ out) {
    int gid = blockIdx.x * blockDim.x + threadIdx.x;
    int n = gid >> 6;
    int j = gid & 63;
    if (n >= N_NODES) return;
    int jc = min(j, N_CLS - 1);           // clamp so loads stay in-bounds
    int beg = rowptr[n], end = rowptr[n + 1];
    float acc = 0.f;
    int i = beg;
    for (; i + 1 < end; i += 2) {
        int s0 = csr[i], s1 = csr[i + 1];
        float v0 = y2[(size_t)s0 * N_CLS + jc];
        float v1 = y2[(size_t)s1 * N_CLS + jc];
        acc += v0 + v1;
    }
    if (i < end) acc += y2[(size_t)csr[i] * N_CLS + jc];

    float val = -INFINITY;
    if (j < N_CLS) {
        float inv = 1.0f / fmaxf((float)(end - beg), 1.0f);
        val = fmaf(acc, inv, b2[j] + z2[(size_t)n * N_CLS + j]);
    }
    float m = val;
#pragma unroll
    for (int off = 32; off > 0; off >>= 1)
        m = fmaxf(m, __shfl_xor(m, off, 64));
    float ex = (j < N_CLS) ? expf(val - m) : 0.0f;
    float s = ex;
#pragma unroll
    for (int off = 32; off > 0; off >>= 1)
        s += __shfl_xor(s, off, 64);
    if (j < N_CLS) out[(size_t)n * N_CLS + j] = val - m - logf(s);
}

extern "C" void kernel_launch(void* const* d_in, const int* in_sizes, int n_in,
                              void* d_out, int out_size, void* d_ws, size_t ws_size,
                              hipStream_t stream) {
    const float* x   = (const float*)d_in[0];
    const int*   ei  = (const int*)d_in[1];
    const float* W1l = (const float*)d_in[2];
    const float* b1  = (const float*)d_in[3];
    const float* W1r = (const float*)d_in[4];
    const float* W2l = (const float*)d_in[5];
    const float* b2  = (const float*)d_in[6];
    const float* W2r = (const float*)d_in[7];
    float* out = (float*)d_out;
    const int E = in_sizes[1] / 2;

    // Workspace layout
    char* p = (char*)d_ws;
    int* deg    = (int*)p;               p += sizeof(int) * N_NODES;
    int* rowptr = (int*)p;               p += sizeof(int) * (N_NODES + 1);
    int* wofs   = (int*)p;               p += sizeof(int) * N_NODES;
    int* csr    = (int*)p;               p += sizeof(int) * E;
    float* y1   = (float*)p;             p += sizeof(float) * (size_t)N_NODES * HID;
    float* z1   = (float*)p;             p += sizeof(float) * (size_t)N_NODES * HID;
    float* h    = (float*)p;             p += sizeof(float) * (size_t)N_NODES * HID;
    // After agg1, y1/z1 are dead: reuse for y2/z2 (N*40 <= N*64).
    float* y2 = y1;
    float* z2 = z1;

    hipMemsetAsync(deg, 0, sizeof(int) * N_NODES, stream);

    const int B = 256;
    int t_nodes64 = N_NODES * 64;

    hist_kernel<<<(E + B - 1) / B, B, 0, stream>>>(ei, E, deg);
    scan_kernel<<<1, SCAN_T, 0, stream>>>(deg, rowptr, wofs);
    fill_kernel<<<(E + B - 1) / B, B, 0, stream>>>(ei, E, wofs, csr);

    gemm1_kernel<<<(t_nodes64 + B - 1) / B, B, 0, stream>>>(x, W1l, W1r, y1, z1);
    agg1_kernel<<<(t_nodes64 + B - 1) / B, B, 0, stream>>>(rowptr, csr, y1, z1, b1, h);
    gemm2_kernel<<<(t_nodes64 + B - 1) / B, B, 0, stream>>>(h, W2l, W2r, y2, z2);
    agg2_kernel<<<(t_nodes64 + B - 1) / B, B, 0, stream>>>(rowptr, csr, y2, z2, b2, out);
}

// Round 3
// 939.364 us; speedup vs baseline: 3.1193x; 1.2147x over previous
//
#include <hip/hip_runtime.h>
#include <math.h>

#define N_NODES 100000
#define F_IN    128
#define HID     64
#define N_CLS   40
#define NPW     8        // nodes per wave in the GEMM kernels (100000 % 8 == 0)
#define SCAN_T  1024
#define SCAN_CH ((N_NODES + SCAN_T - 1) / SCAN_T)   // 98

// ---------------------------------------------------------------------------
// CSR build step 1: in-degree histogram
// ---------------------------------------------------------------------------
__global__ void hist_kernel(const int* __restrict__ ei, int E,
                            int* __restrict__ deg) {
    int e = blockIdx.x * blockDim.x + threadIdx.x;
    if (e < E) atomicAdd(&deg[ei[E + e]], 1);
}

// ---------------------------------------------------------------------------
// CSR build step 2: exclusive prefix scan (single workgroup).
// ---------------------------------------------------------------------------
__global__ void scan_kernel(const int* __restrict__ deg,
                            int* __restrict__ rowptr,
                            int* __restrict__ wofs) {
    __shared__ int ssum[SCAN_T];
    int t = threadIdx.x;
    int lo = t * SCAN_CH;
    int hi = min(lo + SCAN_CH, N_NODES);
    int s = 0;
    for (int i = lo; i < hi; ++i) s += deg[i];
    ssum[t] = s;
    __syncthreads();
    for (int off = 1; off < SCAN_T; off <<= 1) {
        int v = (t >= off) ? ssum[t - off] : 0;
        __syncthreads();
        ssum[t] += v;
        __syncthreads();
    }
    int run = (t > 0) ? ssum[t - 1] : 0;
    for (int i = lo; i < hi; ++i) {
        rowptr[i] = run;
        wofs[i] = run;
        run += deg[i];
    }
    if (t == 0) rowptr[N_NODES] = ssum[SCAN_T - 1];
}

// ---------------------------------------------------------------------------
// CSR build step 3: bucket fill (src ids grouped by dst)
// ---------------------------------------------------------------------------
__global__ void fill_kernel(const int* __restrict__ ei, int E,
                            int* __restrict__ wofs,
                            int* __restrict__ csr) {
    int e = blockIdx.x * blockDim.x + threadIdx.x;
    if (e >= E) return;
    int src = ei[e];
    int dst = ei[E + e];
    int p = atomicAdd(&wofs[dst], 1);
    csr[p] = src;
}

// ---------------------------------------------------------------------------
// gemm1: y1 = x @ W1_l, z1 = x @ W1_r     [N,128]x[128,64] -> [N,64]
// One wave per 8 nodes; lane j = output column. Each W element loaded once
// per wave feeds 8 FMAs (16 FLOP / 4 B) -> W L2 traffic / 8 vs 1-node/wave.
// ---------------------------------------------------------------------------
__global__ void gemm1_kernel(const float* __restrict__ x,
                             const float* __restrict__ Wl,
                             const float* __restrict__ Wr,
                             float* __restrict__ y1,
                             float* __restrict__ z1) {
    int gid = blockIdx.x * blockDim.x + threadIdx.x;
    int wave = gid >> 6;
    int j = gid & 63;
    int n0 = wave * NPW;
    if (n0 >= N_NODES) return;

    float accl[NPW], accr[NPW];
#pragma unroll
    for (int i = 0; i < NPW; ++i) { accl[i] = 0.f; accr[i] = 0.f; }

    for (int k4 = 0; k4 < F_IN / 4; ++k4) {
        float4 xv[NPW];
#pragma unroll
        for (int i = 0; i < NPW; ++i)
            xv[i] = *(const float4*)(x + (size_t)(n0 + i) * F_IN + k4 * 4);
        int k = k4 * 4;
#pragma unroll
        for (int kk = 0; kk < 4; ++kk) {
            float wl = Wl[(k + kk) * HID + j];
            float wr = Wr[(k + kk) * HID + j];
#pragma unroll
            for (int i = 0; i < NPW; ++i) {
                float xs = (kk == 0) ? xv[i].x : (kk == 1) ? xv[i].y
                         : (kk == 2) ? xv[i].z : xv[i].w;
                accl[i] = fmaf(xs, wl, accl[i]);
                accr[i] = fmaf(xs, wr, accr[i]);
            }
        }
    }
#pragma unroll
    for (int i = 0; i < NPW; ++i) {
        y1[(size_t)(n0 + i) * HID + j] = accl[i];
        z1[(size_t)(n0 + i) * HID + j] = accr[i];
    }
}

// ---------------------------------------------------------------------------
// agg1 (+ fused epi): h = relu(mean_{src in N(n)} y1[src] + b1 + z1[n])
// ---------------------------------------------------------------------------
__global__ void agg1_kernel(const int* __restrict__ rowptr,
                            const int* __restrict__ csr,
                            const float* __restrict__ y1,
                            const float* __restrict__ z1,
                            const float* __restrict__ b1,
                            float* __restrict__ h) {
    int gid = blockIdx.x * blockDim.x + threadIdx.x;
    int n = gid >> 6;
    int j = gid & 63;
    if (n >= N_NODES) return;
    int beg = rowptr[n], end = rowptr[n + 1];
    float acc = 0.f;
    int i = beg;
    for (; i + 1 < end; i += 2) {
        int s0 = csr[i], s1 = csr[i + 1];
        float v0 = y1[(size_t)s0 * HID + j];
        float v1 = y1[(size_t)s1 * HID + j];
        acc += v0 + v1;
    }
    if (i < end) acc += y1[(size_t)csr[i] * HID + j];
    float inv = 1.0f / fmaxf((float)(end - beg), 1.0f);
    float v = fmaf(acc, inv, b1[j] + z1[gid]);
    h[gid] = fmaxf(v, 0.0f);
}

// ---------------------------------------------------------------------------
// gemm2: y2 = h @ W2_l, z2 = h @ W2_r     [N,64]x[64,40] -> [N,40]
// 8 nodes per wave; lanes 0..39 = output classes (j clamped for loads).
// ---------------------------------------------------------------------------
__global__ void gemm2_kernel(const float* __restrict__ h,
                             const float* __restrict__ Wl,
                             const float* __restrict__ Wr,
                             float* __restrict__ y2,
                             float* __restrict__ z2) {
    int gid = blockIdx.x * blockDim.x + threadIdx.x;
    int wave = gid >> 6;
    int j = gid & 63;
    int n0 = wave * NPW;
    if (n0 >= N_NODES) return;
    int jc = min(j, N_CLS - 1);

    float accl[NPW], accr[NPW];
#pragma unroll
    for (int i = 0; i < NPW; ++i) { accl[i] = 0.f; accr[i] = 0.f; }

    for (int k4 = 0; k4 < HID / 4; ++k4) {
        float4 hv[NPW];
#pragma unroll
        for (int i = 0; i < NPW; ++i)
            hv[i] = *(const float4*)(h + (size_t)(n0 + i) * HID + k4 * 4);
        int k = k4 * 4;
#pragma unroll
        for (int kk = 0; kk < 4; ++kk) {
            float wl = Wl[(k + kk) * N_CLS + jc];
            float wr = Wr[(k + kk) * N_CLS + jc];
#pragma unroll
            for (int i = 0; i < NPW; ++i) {
                float hs = (kk == 0) ? hv[i].x : (kk == 1) ? hv[i].y
                         : (kk == 2) ? hv[i].z : hv[i].w;
                accl[i] = fmaf(hs, wl, accl[i]);
                accr[i] = fmaf(hs, wr, accr[i]);
            }
        }
    }
    if (j < N_CLS) {
#pragma unroll
        for (int i = 0; i < NPW; ++i) {
            y2[(size_t)(n0 + i) * N_CLS + j] = accl[i];
            z2[(size_t)(n0 + i) * N_CLS + j] = accr[i];
        }
    }
}

// ---------------------------------------------------------------------------
// agg2 + log_softmax fused. One wave per dst node; lanes 0..39 = classes.
// ---------------------------------------------------------------------------
__global__ void agg2_kernel(const int* __restrict__ rowptr,
                            const int* __restrict__ csr,
                            const float* __restrict__ y2,
                            const float* __restrict__ z2,
                            const float* __restrict__ b2,
                            float* __restrict__ out) {
    int gid = blockIdx.x * blockDim.x + threadIdx.x;
    int n = gid >> 6;
    int j = gid & 63;
    if (n >= N_NODES) return;
    int jc = min(j, N_CLS - 1);
    int beg = rowptr[n], end = rowptr[n + 1];
    float acc = 0.f;
    int i = beg;
    for (; i + 1 < end; i += 2) {
        int s0 = csr[i], s1 = csr[i + 1];
        float v0 = y2[(size_t)s0 * N_CLS + jc];
        float v1 = y2[(size_t)s1 * N_CLS + jc];
        acc += v0 + v1;
    }
    if (i < end) acc += y2[(size_t)csr[i] * N_CLS + jc];

    float val = -INFINITY;
    if (j < N_CLS) {
        float inv = 1.0f / fmaxf((float)(end - beg), 1.0f);
        val = fmaf(acc, inv, b2[j] + z2[(size_t)n * N_CLS + j]);
    }
    float m = val;
#pragma unroll
    for (int off = 32; off > 0; off >>= 1)
        m = fmaxf(m, __shfl_xor(m, off, 64));
    float ex = (j < N_CLS) ? expf(val - m) : 0.0f;
    float s = ex;
#pragma unroll
    for (int off = 32; off > 0; off >>= 1)
        s += __shfl_xor(s, off, 64);
    if (j < N_CLS) out[(size_t)n * N_CLS + j] = val - m - logf(s);
}

extern "C" void kernel_launch(void* const* d_in, const int* in_sizes, int n_in,
                              void* d_out, int out_size, void* d_ws, size_t ws_size,
                              hipStream_t stream) {
    const float* x   = (const float*)d_in[0];
    const int*   ei  = (const int*)d_in[1];
    const float* W1l = (const float*)d_in[2];
    const float* b1  = (const float*)d_in[3];
    const float* W1r = (const float*)d_in[4];
    const float* W2l = (const float*)d_in[5];
    const float* b2  = (const float*)d_in[6];
    const float* W2r = (const float*)d_in[7];
    float* out = (float*)d_out;
    const int E = in_sizes[1] / 2;

    // Workspace layout
    char* p = (char*)d_ws;
    int* deg    = (int*)p;               p += sizeof(int) * N_NODES;
    int* rowptr = (int*)p;               p += sizeof(int) * (N_NODES + 1);
    int* wofs   = (int*)p;               p += sizeof(int) * N_NODES;
    int* csr    = (int*)p;               p += sizeof(int) * E;
    float* y1   = (float*)p;             p += sizeof(float) * (size_t)N_NODES * HID;
    float* z1   = (float*)p;             p += sizeof(float) * (size_t)N_NODES * HID;
    float* h    = (float*)p;             p += sizeof(float) * (size_t)N_NODES * HID;
    float* y2 = y1;   // y1/z1 dead after agg1
    float* z2 = z1;

    hipMemsetAsync(deg, 0, sizeof(int) * N_NODES, stream);

    const int B = 256;

    hist_kernel<<<(E + B - 1) / B, B, 0, stream>>>(ei, E, deg);
    scan_kernel<<<1, SCAN_T, 0, stream>>>(deg, rowptr, wofs);
    fill_kernel<<<(E + B - 1) / B, B, 0, stream>>>(ei, E, wofs, csr);

    int t_gemm = (N_NODES / NPW) * 64;          // one wave per 8 nodes
    int t_nodes64 = N_NODES * 64;               // one wave per node

    gemm1_kernel<<<(t_gemm + B - 1) / B, B, 0, stream>>>(x, W1l, W1r, y1, z1);
    agg1_kernel<<<(t_nodes64 + B - 1) / B, B, 0, stream>>>(rowptr, csr, y1, z1, b1, h);
    gemm2_kernel<<<(t_gemm + B - 1) / B, B, 0, stream>>>(h, W2l, W2r, y2, z2);
    agg2_kernel<<<(t_nodes64 + B - 1) / B, B, 0, stream>>>(rowptr, csr, y2, z2, b2, out);
}

// Round 4
// 727.158 us; speedup vs baseline: 4.0296x; 1.2918x over previous
//
#include <hip/hip_runtime.h>
#include <math.h>

#define N_NODES 100000
#define F_IN    128
#define HID     64
#define N_CLS   40
#define NPW     8        // nodes per wave in the GEMM kernels (100000 % 8 == 0)
#define SBLK    256
#define NBLK    ((N_NODES + SBLK - 1) / SBLK)   // 391

// ---------------------------------------------------------------------------
// CSR build step 1: in-degree histogram
// ---------------------------------------------------------------------------
__global__ void hist_kernel(const int* __restrict__ ei, int E,
                            int* __restrict__ deg) {
    int e = blockIdx.x * blockDim.x + threadIdx.x;
    if (e < E) atomicAdd(&deg[ei[E + e]], 1);
}

// ---------------------------------------------------------------------------
// CSR build 2a: per-block sums of deg (391 blocks x 256)
// ---------------------------------------------------------------------------
__global__ void blocksum_kernel(const int* __restrict__ deg,
                                int* __restrict__ bsum) {
    __shared__ int sd[SBLK];
    int t = threadIdx.x;
    int i = blockIdx.x * SBLK + t;
    sd[t] = (i < N_NODES) ? deg[i] : 0;
    __syncthreads();
    for (int s = SBLK / 2; s > 0; s >>= 1) {
        if (t < s) sd[t] += sd[t + s];
        __syncthreads();
    }
    if (t == 0) bsum[blockIdx.x] = sd[0];
}

// ---------------------------------------------------------------------------
// CSR build 2b: exclusive scan over the 391 block sums (1 block x 512)
// ---------------------------------------------------------------------------
__global__ void scan_bsum_kernel(const int* __restrict__ bsum,
                                 int* __restrict__ ebsum,
                                 int* __restrict__ rowptr) {
    __shared__ int ss[512];
    int t = threadIdx.x;
    int v = (t < NBLK) ? bsum[t] : 0;
    ss[t] = v;
    __syncthreads();
    for (int off = 1; off < 512; off <<= 1) {
        int u = (t >= off) ? ss[t - off] : 0;
        __syncthreads();
        ss[t] += u;
        __syncthreads();
    }
    if (t < NBLK) ebsum[t] = ss[t] - v;        // exclusive
    if (t == 0) rowptr[N_NODES] = ss[NBLK - 1]; // total = E
}

// ---------------------------------------------------------------------------
// CSR build 2c: block-local exclusive scan + block offset -> rowptr/wofs
// ---------------------------------------------------------------------------
__global__ void local_scan_kernel(const int* __restrict__ deg,
                                  const int* __restrict__ ebsum,
                                  int* __restrict__ rowptr,
                                  int* __restrict__ wofs) {
    __shared__ int ss[SBLK];
    int t = threadIdx.x;
    int i = blockIdx.x * SBLK + t;
    int v = (i < N_NODES) ? deg[i] : 0;
    ss[t] = v;
    __syncthreads();
    for (int off = 1; off < SBLK; off <<= 1) {
        int u = (t >= off) ? ss[t - off] : 0;
        __syncthreads();
        ss[t] += u;
        __syncthreads();
    }
    if (i < N_NODES) {
        int ex = ebsum[blockIdx.x] + ss[t] - v;
        rowptr[i] = ex;
        wofs[i] = ex;
    }
}

// ---------------------------------------------------------------------------
// CSR build step 3: bucket fill (src ids grouped by dst)
// ---------------------------------------------------------------------------
__global__ void fill_kernel(const int* __restrict__ ei, int E,
                            int* __restrict__ wofs,
                            int* __restrict__ csr) {
    int e = blockIdx.x * blockDim.x + threadIdx.x;
    if (e >= E) return;
    int src = ei[e];
    int dst = ei[E + e];
    int p = atomicAdd(&wofs[dst], 1);
    csr[p] = src;
}

// ---------------------------------------------------------------------------
// gemm1: y1 = x @ W1_l, z1 = x @ W1_r     [N,128]x[128,64] -> [N,64]
// One wave per 8 nodes; lane j = output column. Each W element loaded once
// per wave feeds 8 FMAs per matrix -> W L2 traffic / 8 vs 1-node/wave.
// ---------------------------------------------------------------------------
__global__ void gemm1_kernel(const float* __restrict__ x,
                             const float* __restrict__ Wl,
                             const float* __restrict__ Wr,
                             float* __restrict__ y1,
                             float* __restrict__ z1) {
    int gid = blockIdx.x * blockDim.x + threadIdx.x;
    int wave = gid >> 6;
    int j = gid & 63;
    int n0 = wave * NPW;
    if (n0 >= N_NODES) return;

    float accl[NPW], accr[NPW];
#pragma unroll
    for (int i = 0; i < NPW; ++i) { accl[i] = 0.f; accr[i] = 0.f; }

    for (int k4 = 0; k4 < F_IN / 4; ++k4) {
        float4 xv[NPW];
#pragma unroll
        for (int i = 0; i < NPW; ++i)
            xv[i] = *(const float4*)(x + (size_t)(n0 + i) * F_IN + k4 * 4);
        int k = k4 * 4;
#pragma unroll
        for (int kk = 0; kk < 4; ++kk) {
            float wl = Wl[(k + kk) * HID + j];
            float wr = Wr[(k + kk) * HID + j];
#pragma unroll
            for (int i = 0; i < NPW; ++i) {
                float xs = (kk == 0) ? xv[i].x : (kk == 1) ? xv[i].y
                         : (kk == 2) ? xv[i].z : xv[i].w;
                accl[i] = fmaf(xs, wl, accl[i]);
                accr[i] = fmaf(xs, wr, accr[i]);
            }
        }
    }
#pragma unroll
    for (int i = 0; i < NPW; ++i) {
        y1[(size_t)(n0 + i) * HID + j] = accl[i];
        z1[(size_t)(n0 + i) * HID + j] = accr[i];
    }
}

// ---------------------------------------------------------------------------
// agg1 (+ fused epi): h = relu(mean_{src in N(n)} y1[src] + b1 + z1[n])
// ---------------------------------------------------------------------------
__global__ void agg1_kernel(const int* __restrict__ rowptr,
                            const int* __restrict__ csr,
                            const float* __restrict__ y1,
                            const float* __restrict__ z1,
                            const float* __restrict__ b1,
                            float* __restrict__ h) {
    int gid = blockIdx.x * blockDim.x + threadIdx.x;
    int n = gid >> 6;
    int j = gid & 63;
    if (n >= N_NODES) return;
    int beg = rowptr[n], end = rowptr[n + 1];
    float acc = 0.f;
    int i = beg;
    for (; i + 1 < end; i += 2) {
        int s0 = csr[i], s1 = csr[i + 1];
        float v0 = y1[(size_t)s0 * HID + j];
        float v1 = y1[(size_t)s1 * HID + j];
        acc += v0 + v1;
    }
    if (i < end) acc += y1[(size_t)csr[i] * HID + j];
    float inv = 1.0f / fmaxf((float)(end - beg), 1.0f);
    float v = fmaf(acc, inv, b1[j] + z1[gid]);
    h[gid] = fmaxf(v, 0.0f);
}

// ---------------------------------------------------------------------------
// gemm2: y2 = h @ W2_l, z2 = h @ W2_r     [N,64]x[64,40] -> [N,40]
// 8 nodes per wave; lanes 0..39 = output classes (j clamped for loads).
// ---------------------------------------------------------------------------
__global__ void gemm2_kernel(const float* __restrict__ h,
                             const float* __restrict__ Wl,
                             const float* __restrict__ Wr,
                             float* __restrict__ y2,
                             float* __restrict__ z2) {
    int gid = blockIdx.x * blockDim.x + threadIdx.x;
    int wave = gid >> 6;
    int j = gid & 63;
    int n0 = wave * NPW;
    if (n0 >= N_NODES) return;
    int jc = min(j, N_CLS - 1);

    float accl[NPW], accr[NPW];
#pragma unroll
    for (int i = 0; i < NPW; ++i) { accl[i] = 0.f; accr[i] = 0.f; }

    for (int k4 = 0; k4 < HID / 4; ++k4) {
        float4 hv[NPW];
#pragma unroll
        for (int i = 0; i < NPW; ++i)
            hv[i] = *(const float4*)(h + (size_t)(n0 + i) * HID + k4 * 4);
        int k = k4 * 4;
#pragma unroll
        for (int kk = 0; kk < 4; ++kk) {
            float wl = Wl[(k + kk) * N_CLS + jc];
            float wr = Wr[(k + kk) * N_CLS + jc];
#pragma unroll
            for (int i = 0; i < NPW; ++i) {
                float hs = (kk == 0) ? hv[i].x : (kk == 1) ? hv[i].y
                         : (kk == 2) ? hv[i].z : hv[i].w;
                accl[i] = fmaf(hs, wl, accl[i]);
                accr[i] = fmaf(hs, wr, accr[i]);
            }
        }
    }
    if (j < N_CLS) {
#pragma unroll
        for (int i = 0; i < NPW; ++i) {
            y2[(size_t)(n0 + i) * N_CLS + j] = accl[i];
            z2[(size_t)(n0 + i) * N_CLS + j] = accr[i];
        }
    }
}

// ---------------------------------------------------------------------------
// agg2 + log_softmax fused. One wave per dst node; lanes 0..39 = classes.
// ---------------------------------------------------------------------------
__global__ void agg2_kernel(const int* __restrict__ rowptr,
                            const int* __restrict__ csr,
                            const float* __restrict__ y2,
                            const float* __restrict__ z2,
                            const float* __restrict__ b2,
                            float* __restrict__ out) {
    int gid = blockIdx.x * blockDim.x + threadIdx.x;
    int n = gid >> 6;
    int j = gid & 63;
    if (n >= N_NODES) return;
    int jc = min(j, N_CLS - 1);
    int beg = rowptr[n], end = rowptr[n + 1];
    float acc = 0.f;
    int i = beg;
    for (; i + 1 < end; i += 2) {
        int s0 = csr[i], s1 = csr[i + 1];
        float v0 = y2[(size_t)s0 * N_CLS + jc];
        float v1 = y2[(size_t)s1 * N_CLS + jc];
        acc += v0 + v1;
    }
    if (i < end) acc += y2[(size_t)csr[i] * N_CLS + jc];

    float val = -INFINITY;
    if (j < N_CLS) {
        float inv = 1.0f / fmaxf((float)(end - beg), 1.0f);
        val = fmaf(acc, inv, b2[j] + z2[(size_t)n * N_CLS + j]);
    }
    float m = val;
#pragma unroll
    for (int off = 32; off > 0; off >>= 1)
        m = fmaxf(m, __shfl_xor(m, off, 64));
    float ex = (j < N_CLS) ? expf(val - m) : 0.0f;
    float s = ex;
#pragma unroll
    for (int off = 32; off > 0; off >>= 1)
        s += __shfl_xor(s, off, 64);
    if (j < N_CLS) out[(size_t)n * N_CLS + j] = val - m - logf(s);
}

extern "C" void kernel_launch(void* const* d_in, const int* in_sizes, int n_in,
                              void* d_out, int out_size, void* d_ws, size_t ws_size,
                              hipStream_t stream) {
    const float* x   = (const float*)d_in[0];
    const int*   ei  = (const int*)d_in[1];
    const float* W1l = (const float*)d_in[2];
    const float* b1  = (const float*)d_in[3];
    const float* W1r = (const float*)d_in[4];
    const float* W2l = (const float*)d_in[5];
    const float* b2  = (const float*)d_in[6];
    const float* W2r = (const float*)d_in[7];
    float* out = (float*)d_out;
    const int E = in_sizes[1] / 2;

    // Workspace layout
    char* p = (char*)d_ws;
    int* deg    = (int*)p;               p += sizeof(int) * N_NODES;
    int* rowptr = (int*)p;               p += sizeof(int) * (N_NODES + 1);
    int* wofs   = (int*)p;               p += sizeof(int) * N_NODES;
    int* bsum   = (int*)p;               p += sizeof(int) * 512;
    int* ebsum  = (int*)p;               p += sizeof(int) * 512;
    int* csr    = (int*)p;               p += sizeof(int) * E;
    float* y1   = (float*)p;             p += sizeof(float) * (size_t)N_NODES * HID;
    float* z1   = (float*)p;             p += sizeof(float) * (size_t)N_NODES * HID;
    float* h    = (float*)p;             p += sizeof(float) * (size_t)N_NODES * HID;
    float* y2 = y1;   // y1/z1 dead after agg1
    float* z2 = z1;

    hipMemsetAsync(deg, 0, sizeof(int) * N_NODES, stream);

    const int B = 256;

    hist_kernel<<<(E + B - 1) / B, B, 0, stream>>>(ei, E, deg);
    blocksum_kernel<<<NBLK, SBLK, 0, stream>>>(deg, bsum);
    scan_bsum_kernel<<<1, 512, 0, stream>>>(bsum, ebsum, rowptr);
    local_scan_kernel<<<NBLK, SBLK, 0, stream>>>(deg, ebsum, rowptr, wofs);
    fill_kernel<<<(E + B - 1) / B, B, 0, stream>>>(ei, E, wofs, csr);

    int t_gemm = (N_NODES / NPW) * 64;          // one wave per 8 nodes
    int t_nodes64 = N_NODES * 64;               // one wave per node

    gemm1_kernel<<<(t_gemm + B - 1) / B, B, 0, stream>>>(x, W1l, W1r, y1, z1);
    agg1_kernel<<<(t_nodes64 + B - 1) / B, B, 0, stream>>>(rowptr, csr, y1, z1, b1, h);
    gemm2_kernel<<<(t_gemm + B - 1) / B, B, 0, stream>>>(h, W2l, W2r, y2, z2);
    agg2_kernel<<<(t_nodes64 + B - 1) / B, B, 0, stream>>>(rowptr, csr, y2, z2, b2, out);
}

// Round 5
// 551.563 us; speedup vs baseline: 5.3124x; 1.3184x over previous
//
#include <hip/hip_runtime.h>
#include <math.h>

#define N_NODES 100000
#define F_IN    128
#define HID     64
#define N_CLS   40
#define SBLK    256
#define NBLK    ((N_NODES + SBLK - 1) / SBLK)   // 391
#define MT      (N_NODES / 16)                  // 6250 M-tiles of 16 nodes

typedef __attribute__((ext_vector_type(8))) short bf8_t;   // 8 bf16 (4 VGPR)
typedef __attribute__((ext_vector_type(4))) float f4_t;    // MFMA C/D frag

typedef unsigned short ushort_t;
typedef unsigned int uint_t;

__device__ __forceinline__ ushort_t f2b(float f) {   // f32 -> bf16 RNE
    union { float f; uint_t u; } c; c.f = f;
    uint_t u = c.u + 0x7FFFu + ((c.u >> 16) & 1u);
    return (ushort_t)(u >> 16);
}
__device__ __forceinline__ float b2f(ushort_t h) {
    union { uint_t u; float f; } c; c.u = ((uint_t)h) << 16;
    return c.f;
}

// ---------------------------------------------------------------------------
// CSR build step 1: in-degree histogram
// ---------------------------------------------------------------------------
__global__ void hist_kernel(const int* __restrict__ ei, int E,
                            int* __restrict__ deg) {
    int e = blockIdx.x * blockDim.x + threadIdx.x;
    if (e < E) atomicAdd(&deg[ei[E + e]], 1);
}

// ---------------------------------------------------------------------------
// CSR build 2a/2b/2c: 3-phase parallel exclusive scan of deg -> rowptr/wofs
// ---------------------------------------------------------------------------
__global__ void blocksum_kernel(const int* __restrict__ deg,
                                int* __restrict__ bsum) {
    __shared__ int sd[SBLK];
    int t = threadIdx.x;
    int i = blockIdx.x * SBLK + t;
    sd[t] = (i < N_NODES) ? deg[i] : 0;
    __syncthreads();
    for (int s = SBLK / 2; s > 0; s >>= 1) {
        if (t < s) sd[t] += sd[t + s];
        __syncthreads();
    }
    if (t == 0) bsum[blockIdx.x] = sd[0];
}

__global__ void scan_bsum_kernel(const int* __restrict__ bsum,
                                 int* __restrict__ ebsum,
                                 int* __restrict__ rowptr) {
    __shared__ int ss[512];
    int t = threadIdx.x;
    int v = (t < NBLK) ? bsum[t] : 0;
    ss[t] = v;
    __syncthreads();
    for (int off = 1; off < 512; off <<= 1) {
        int u = (t >= off) ? ss[t - off] : 0;
        __syncthreads();
        ss[t] += u;
        __syncthreads();
    }
    if (t < NBLK) ebsum[t] = ss[t] - v;
    if (t == 0) rowptr[N_NODES] = ss[NBLK - 1];
}

__global__ void local_scan_kernel(const int* __restrict__ deg,
                                  const int* __restrict__ ebsum,
                                  int* __restrict__ rowptr,
                                  int* __restrict__ wofs) {
    __shared__ int ss[SBLK];
    int t = threadIdx.x;
    int i = blockIdx.x * SBLK + t;
    int v = (i < N_NODES) ? deg[i] : 0;
    ss[t] = v;
    __syncthreads();
    for (int off = 1; off < SBLK; off <<= 1) {
        int u = (t >= off) ? ss[t - off] : 0;
        __syncthreads();
        ss[t] += u;
        __syncthreads();
    }
    if (i < N_NODES) {
        int ex = ebsum[blockIdx.x] + ss[t] - v;
        rowptr[i] = ex;
        wofs[i] = ex;
    }
}

// ---------------------------------------------------------------------------
// CSR build step 3: bucket fill (src ids grouped by dst)
// ---------------------------------------------------------------------------
__global__ void fill_kernel(const int* __restrict__ ei, int E,
                            int* __restrict__ wofs,
                            int* __restrict__ csr) {
    int e = blockIdx.x * blockDim.x + threadIdx.x;
    if (e >= E) return;
    int src = ei[e];
    int dst = ei[E + e];
    int p = atomicAdd(&wofs[dst], 1);
    csr[p] = src;
}

// ---------------------------------------------------------------------------
// cvt_w: build bf16, [n][k]-major (B-fragment friendly) weight tensors.
// W1t[128][128]: n<64 -> W1_l col n, n>=64 -> W1_r col n-64.
// W2t[80][64]:   n<40 -> W2_l col n, n>=40 -> W2_r col n-40.
// ---------------------------------------------------------------------------
__global__ void cvt_w_kernel(const float* __restrict__ W1l,
                             const float* __restrict__ W1r,
                             const float* __restrict__ W2l,
                             const float* __restrict__ W2r,
                             ushort_t* __restrict__ W1t,
                             ushort_t* __restrict__ W2t) {
    int t = blockIdx.x * blockDim.x + threadIdx.x;
    if (t < 128 * F_IN) {
        int n = t / F_IN, k = t - n * F_IN;
        float v = (n < HID) ? W1l[k * HID + n] : W1r[k * HID + (n - HID)];
        W1t[t] = f2b(v);
    } else if (t < 128 * F_IN + 80 * HID) {
        int u = t - 128 * F_IN;
        int n = u / HID, k = u - n * HID;
        float v = (n < N_CLS) ? W2l[k * N_CLS + n] : W2r[k * N_CLS + (n - N_CLS)];
        W2t[u] = f2b(v);
    }
}

// ---------------------------------------------------------------------------
// gemm1_mfma: [y1b|z1b] = x @ [W1_l|W1_r]  via mfma_f32_16x16x32_bf16.
// One wave per 16-node M-tile; loops 8 N-tiles (128 outputs) so x is
// fetched once. A-frag built inline from f32 x (RNE to bf16).
// Frag layouts (verified, guide §3): A/B lane holds row/col lane&15,
// k = (lane>>4)*8 + j; D: col = lane&15, row = (lane>>4)*4 + reg.
// ---------------------------------------------------------------------------
__global__ void gemm1_mfma_kernel(const float* __restrict__ x,
                                  const ushort_t* __restrict__ W1t,
                                  ushort_t* __restrict__ y1b,
                                  ushort_t* __restrict__ z1b) {
    int gid = blockIdx.x * blockDim.x + threadIdx.x;
    int wave = gid >> 6, lane = gid & 63;
    if (wave >= MT) return;
    int m0 = wave * 16;
    int r = lane & 15, q = lane >> 4;

    const float* xr = x + (size_t)(m0 + r) * F_IN + q * 8;
    bf8_t a[4];
#pragma unroll
    for (int kt = 0; kt < 4; ++kt) {
        float4 u = *(const float4*)(xr + kt * 32);
        float4 v = *(const float4*)(xr + kt * 32 + 4);
        bf8_t t;
        t[0] = (short)f2b(u.x); t[1] = (short)f2b(u.y);
        t[2] = (short)f2b(u.z); t[3] = (short)f2b(u.w);
        t[4] = (short)f2b(v.x); t[5] = (short)f2b(v.y);
        t[6] = (short)f2b(v.z); t[7] = (short)f2b(v.w);
        a[kt] = t;
    }
#pragma unroll
    for (int tn = 0; tn < 8; ++tn) {
        const ushort_t* wr = W1t + (size_t)(tn * 16 + r) * F_IN + q * 8;
        f4_t acc = {0.f, 0.f, 0.f, 0.f};
#pragma unroll
        for (int kt = 0; kt < 4; ++kt) {
            bf8_t b = *(const bf8_t*)(wr + kt * 32);
            acc = __builtin_amdgcn_mfma_f32_16x16x32_bf16(a[kt], b, acc, 0, 0, 0);
        }
        int col = tn * 16 + r;
        ushort_t* dst = (col < HID) ? (y1b + col) : (z1b + (col - HID));
#pragma unroll
        for (int rr = 0; rr < 4; ++rr) {
            int row = m0 + q * 4 + rr;
            dst[(size_t)row * HID] = f2b(acc[rr]);
        }
    }
}

// ---------------------------------------------------------------------------
// agg1 (+ fused epi): h = relu(mean y1[src] + b1 + z1)   [bf16 in, bf16 out]
// ---------------------------------------------------------------------------
__global__ void agg1_kernel(const int* __restrict__ rowptr,
                            const int* __restrict__ csr,
                            const ushort_t* __restrict__ y1b,
                            const ushort_t* __restrict__ z1b,
                            const float* __restrict__ b1,
                            ushort_t* __restrict__ hb) {
    int gid = blockIdx.x * blockDim.x + threadIdx.x;
    int n = gid >> 6;
    int j = gid & 63;
    if (n >= N_NODES) return;
    int beg = rowptr[n], end = rowptr[n + 1];
    float acc = 0.f;
    int i = beg;
    for (; i + 1 < end; i += 2) {
        int s0 = csr[i], s1 = csr[i + 1];
        float v0 = b2f(y1b[(size_t)s0 * HID + j]);
        float v1 = b2f(y1b[(size_t)s1 * HID + j]);
        acc += v0 + v1;
    }
    if (i < end) acc += b2f(y1b[(size_t)csr[i] * HID + j]);
    float inv = 1.0f / fmaxf((float)(end - beg), 1.0f);
    float v = fmaf(acc, inv, b1[j] + b2f(z1b[gid]));
    hb[gid] = f2b(fmaxf(v, 0.0f));
}

// ---------------------------------------------------------------------------
// gemm2_mfma: [y2b|z2b] = h @ [W2_l|W2_r]   K=64, N=80 (5 tiles of 16).
// ---------------------------------------------------------------------------
__global__ void gemm2_mfma_kernel(const ushort_t* __restrict__ hb,
                                  const ushort_t* __restrict__ W2t,
                                  ushort_t* __restrict__ y2b,
                                  ushort_t* __restrict__ z2b) {
    int gid = blockIdx.x * blockDim.x + threadIdx.x;
    int wave = gid >> 6, lane = gid & 63;
    if (wave >= MT) return;
    int m0 = wave * 16;
    int r = lane & 15, q = lane >> 4;

    const ushort_t* hr = hb + (size_t)(m0 + r) * HID + q * 8;
    bf8_t a[2];
#pragma unroll
    for (int kt = 0; kt < 2; ++kt)
        a[kt] = *(const bf8_t*)(hr + kt * 32);

#pragma unroll
    for (int tn = 0; tn < 5; ++tn) {
        const ushort_t* wr = W2t + (size_t)(tn * 16 + r) * HID + q * 8;
        f4_t acc = {0.f, 0.f, 0.f, 0.f};
#pragma unroll
        for (int kt = 0; kt < 2; ++kt) {
            bf8_t b = *(const bf8_t*)(wr + kt * 32);
            acc = __builtin_amdgcn_mfma_f32_16x16x32_bf16(a[kt], b, acc, 0, 0, 0);
        }
        int col = tn * 16 + r;
        ushort_t* dst = (col < N_CLS) ? (y2b + col) : (z2b + (col - N_CLS));
#pragma unroll
        for (int rr = 0; rr < 4; ++rr) {
            int row = m0 + q * 4 + rr;
            dst[(size_t)row * N_CLS] = f2b(acc[rr]);
        }
    }
}

// ---------------------------------------------------------------------------
// agg2 + log_softmax fused. One wave per dst node; lanes 0..39 = classes.
// ---------------------------------------------------------------------------
__global__ void agg2_kernel(const int* __restrict__ rowptr,
                            const int* __restrict__ csr,
                            const ushort_t* __restrict__ y2b,
                            const ushort_t* __restrict__ z2b,
                            const float* __restrict__ b2,
                            float* __restrict__ out) {
    int gid = blockIdx.x * blockDim.x + threadIdx.x;
    int n = gid >> 6;
    int j = gid & 63;
    if (n >= N_NODES) return;
    int jc = min(j, N_CLS - 1);
    int beg = rowptr[n], end = rowptr[n + 1];
    float acc = 0.f;
    int i = beg;
    for (; i + 1 < end; i += 2) {
        int s0 = csr[i], s1 = csr[i + 1];
        float v0 = b2f(y2b[(size_t)s0 * N_CLS + jc]);
        float v1 = b2f(y2b[(size_t)s1 * N_CLS + jc]);
        acc += v0 + v1;
    }
    if (i < end) acc += b2f(y2b[(size_t)csr[i] * N_CLS + jc]);

    float val = -INFINITY;
    if (j < N_CLS) {
        float inv = 1.0f / fmaxf((float)(end - beg), 1.0f);
        val = fmaf(acc, inv, b2[j] + b2f(z2b[(size_t)n * N_CLS + j]));
    }
    float m = val;
#pragma unroll
    for (int off = 32; off > 0; off >>= 1)
        m = fmaxf(m, __shfl_xor(m, off, 64));
    float ex = (j < N_CLS) ? expf(val - m) : 0.0f;
    float s = ex;
#pragma unroll
    for (int off = 32; off > 0; off >>= 1)
        s += __shfl_xor(s, off, 64);
    if (j < N_CLS) out[(size_t)n * N_CLS + j] = val - m - logf(s);
}

extern "C" void kernel_launch(void* const* d_in, const int* in_sizes, int n_in,
                              void* d_out, int out_size, void* d_ws, size_t ws_size,
                              hipStream_t stream) {
    const float* x   = (const float*)d_in[0];
    const int*   ei  = (const int*)d_in[1];
    const float* W1l = (const float*)d_in[2];
    const float* b1  = (const float*)d_in[3];
    const float* W1r = (const float*)d_in[4];
    const float* W2l = (const float*)d_in[5];
    const float* b2  = (const float*)d_in[6];
    const float* W2r = (const float*)d_in[7];
    float* out = (float*)d_out;
    const int E = in_sizes[1] / 2;

    // Workspace layout (ints first, then 16B-aligned bf16 tensors)
    char* p = (char*)d_ws;
    int* deg    = (int*)p;       p += sizeof(int) * N_NODES;         // 400000
    int* rowptr = (int*)p;       p += sizeof(int) * (N_NODES + 4);   // pad
    int* wofs   = (int*)p;       p += sizeof(int) * N_NODES;
    int* bsum   = (int*)p;       p += sizeof(int) * 512;
    int* ebsum  = (int*)p;       p += sizeof(int) * 512;
    int* csr    = (int*)p;       p += sizeof(int) * ((E + 3) & ~3);
    ushort_t* W1t = (ushort_t*)p; p += sizeof(ushort_t) * 128 * F_IN;
    ushort_t* W2t = (ushort_t*)p; p += sizeof(ushort_t) * 80 * HID;
    ushort_t* y1b = (ushort_t*)p; p += sizeof(ushort_t) * (size_t)N_NODES * HID;
    ushort_t* z1b = (ushort_t*)p; p += sizeof(ushort_t) * (size_t)N_NODES * HID;
    ushort_t* hb  = (ushort_t*)p; p += sizeof(ushort_t) * (size_t)N_NODES * HID;
    // y2b/z2b (N*40 each) alias y1b/z1b (dead after agg1; N*40 < N*64)
    ushort_t* y2b = y1b;
    ushort_t* z2b = z1b;

    hipMemsetAsync(deg, 0, sizeof(int) * N_NODES, stream);

    const int B = 256;

    hist_kernel<<<(E + B - 1) / B, B, 0, stream>>>(ei, E, deg);
    blocksum_kernel<<<NBLK, SBLK, 0, stream>>>(deg, bsum);
    scan_bsum_kernel<<<1, 512, 0, stream>>>(bsum, ebsum, rowptr);
    local_scan_kernel<<<NBLK, SBLK, 0, stream>>>(deg, ebsum, rowptr, wofs);
    fill_kernel<<<(E + B - 1) / B, B, 0, stream>>>(ei, E, wofs, csr);

    cvt_w_kernel<<<(128 * F_IN + 80 * HID + B - 1) / B, B, 0, stream>>>(
        W1l, W1r, W2l, W2r, W1t, W2t);

    int t_mfma = MT * 64;               // one wave per 16-node tile
    int t_nodes64 = N_NODES * 64;       // one wave per node

    gemm1_mfma_kernel<<<(t_mfma + B - 1) / B, B, 0, stream>>>(x, W1t, y1b, z1b);
    agg1_kernel<<<(t_nodes64 + B - 1) / B, B, 0, stream>>>(rowptr, csr, y1b, z1b, b1, hb);
    gemm2_mfma_kernel<<<(t_mfma + B - 1) / B, B, 0, stream>>>(hb, W2t, y2b, z2b);
    agg2_kernel<<<(t_nodes64 + B - 1) / B, B, 0, stream>>>(rowptr, csr, y2b, z2b, b2, out);
}

// Round 6
// 407.422 us; speedup vs baseline: 7.1919x; 1.3538x over previous
//
#include <hip/hip_runtime.h>
#include <math.h>

#define N_NODES 100000
#define F_IN    128
#define HID     64
#define N_CLS   40
#define MT      (N_NODES / 16)                  // 6250 M-tiles of 16 nodes

#define BSHIFT  9
#define BSZ     512                              // dsts per coarse bucket
#define NB      ((N_NODES + BSZ - 1) / BSZ)      // 196 buckets
#define EPB     4096                             // edges per block in sort passes

typedef __attribute__((ext_vector_type(8))) short bf8_t;   // 8 bf16 (4 VGPR)
typedef __attribute__((ext_vector_type(4))) float f4_t;    // MFMA C/D frag

typedef unsigned short ushort_t;
typedef unsigned int uint_t;

__device__ __forceinline__ ushort_t f2b(float f) {   // f32 -> bf16 RNE
    union { float f; uint_t u; } c; c.f = f;
    uint_t u = c.u + 0x7FFFu + ((c.u >> 16) & 1u);
    return (ushort_t)(u >> 16);
}
__device__ __forceinline__ float b2f(ushort_t h) {
    union { uint_t u; float f; } c; c.u = ((uint_t)h) << 16;
    return c.f;
}

// ---------------------------------------------------------------------------
// Sort pass 1: per-block LDS histogram over 196 coarse buckets (dst >> 9).
// No global atomics.
// ---------------------------------------------------------------------------
__global__ void block_hist_kernel(const int* __restrict__ ei, int E,
                                  int* __restrict__ blockHist) {
    __shared__ int cnt[NB];
    int t = threadIdx.x, blk = blockIdx.x;
    for (int i = t; i < NB; i += 256) cnt[i] = 0;
    __syncthreads();
    int e0 = blk * EPB;
#pragma unroll
    for (int i = 0; i < EPB / 256; ++i) {
        int e = e0 + i * 256 + t;
        if (e < E) atomicAdd(&cnt[ei[E + e] >> BSHIFT], 1);
    }
    __syncthreads();
    for (int i = t; i < NB; i += 256) blockHist[blk * NB + i] = cnt[i];
}

// ---------------------------------------------------------------------------
// Sort pass 2: per-bin exclusive scan down the blocks.
// blockBase[blk][bin] = # edges of this bin in earlier blocks; btot[bin]=total.
// One block (256 thr) per bin, chunked scan with running carry.
// ---------------------------------------------------------------------------
__global__ void col_scan_kernel(const int* __restrict__ blockHist, int nblk,
                                int* __restrict__ blockBase,
                                int* __restrict__ btot) {
    __shared__ int ss[256];
    __shared__ int carry;
    int bin = blockIdx.x, t = threadIdx.x;
    if (t == 0) carry = 0;
    __syncthreads();
    for (int c0 = 0; c0 < nblk; c0 += 256) {
        int b = c0 + t;
        int v = (b < nblk) ? blockHist[b * NB + bin] : 0;
        ss[t] = v;
        __syncthreads();
        for (int off = 1; off < 256; off <<= 1) {
            int u = (t >= off) ? ss[t - off] : 0;
            __syncthreads();
            ss[t] += u;
            __syncthreads();
        }
        if (b < nblk) blockBase[b * NB + bin] = carry + ss[t] - v;
        __syncthreads();
        if (t == 255) carry += ss[255];
        __syncthreads();
    }
    if (t == 0) btot[bin] = carry;
}

// ---------------------------------------------------------------------------
// Sort pass 3: exclusive scan over the 196 bucket totals -> bucket offsets.
// Also writes rowptr[N] = E.
// ---------------------------------------------------------------------------
__global__ void bucket_scan_kernel(const int* __restrict__ btot,
                                   int* __restrict__ boff,
                                   int* __restrict__ rowptr) {
    __shared__ int ss[256];
    int t = threadIdx.x;
    int v = (t < NB) ? btot[t] : 0;
    ss[t] = v;
    __syncthreads();
    for (int off = 1; off < 256; off <<= 1) {
        int u = (t >= off) ? ss[t - off] : 0;
        __syncthreads();
        ss[t] += u;
        __syncthreads();
    }
    if (t < NB) boff[t] = ss[t] - v;
    if (t == NB - 1) rowptr[N_NODES] = ss[t];
}

// ---------------------------------------------------------------------------
// Sort pass 4: scatter (src,dst) pairs into coarse-bucket order.
// Block-local LDS cursors; each block's writes per bin are CONTIGUOUS runs.
// No global atomics.
// ---------------------------------------------------------------------------
__global__ void scatter_pairs_kernel(const int* __restrict__ ei, int E,
                                     const int* __restrict__ blockBase,
                                     const int* __restrict__ boff,
                                     int2* __restrict__ pairs) {
    __shared__ int cur[NB];
    __shared__ int base[NB];
    int t = threadIdx.x, blk = blockIdx.x;
    for (int i = t; i < NB; i += 256) {
        cur[i] = 0;
        base[i] = boff[i] + blockBase[blk * NB + i];
    }
    __syncthreads();
    int e0 = blk * EPB;
#pragma unroll
    for (int i = 0; i < EPB / 256; ++i) {
        int e = e0 + i * 256 + t;
        if (e < E) {
            int src = ei[e];
            int dst = ei[E + e];
            int bin = dst >> BSHIFT;
            int r = atomicAdd(&cur[bin], 1);   // LDS atomic
            pairs[base[bin] + r] = make_int2(src, dst);
        }
    }
}

// ---------------------------------------------------------------------------
// Sort pass 5: per-bucket fine sort (512 dst bins). Writes rowptr for its
// 512 dsts and scatters src into a contiguous ~32 KB csr region.
// LDS atomics only.
// ---------------------------------------------------------------------------
__global__ void bucket_sort_kernel(const int2* __restrict__ pairs,
                                   const int* __restrict__ boff,
                                   const int* __restrict__ btot,
                                   int* __restrict__ rowptr,
                                   int* __restrict__ csr) {
    __shared__ int hist[BSZ];
    __shared__ int lofs[BSZ];
    int bin = blockIdx.x, t = threadIdx.x;
    int base = boff[bin], cnt = btot[bin];
    hist[t] = 0;
    __syncthreads();
    for (int i = t; i < cnt; i += BSZ)
        atomicAdd(&hist[pairs[base + i].y & (BSZ - 1)], 1);
    __syncthreads();
    int v = hist[t];
    lofs[t] = v;
    __syncthreads();
    for (int off = 1; off < BSZ; off <<= 1) {
        int u = (t >= off) ? lofs[t - off] : 0;
        __syncthreads();
        lofs[t] += u;
        __syncthreads();
    }
    int excl = lofs[t] - v;
    int d_global = (bin << BSHIFT) + t;
    if (d_global < N_NODES) rowptr[d_global] = base + excl;
    __syncthreads();
    lofs[t] = excl;      // own slot only
    hist[t] = 0;         // reuse as cursor
    __syncthreads();
    for (int i = t; i < cnt; i += BSZ) {
        int2 p = pairs[base + i];
        int lb = p.y & (BSZ - 1);
        int r = atomicAdd(&hist[lb], 1);
        csr[base + lofs[lb] + r] = p.x;
    }
}

// ---------------------------------------------------------------------------
// cvt_w: build bf16, [n][k]-major (B-fragment friendly) weight tensors.
// ---------------------------------------------------------------------------
__global__ void cvt_w_kernel(const float* __restrict__ W1l,
                             const float* __restrict__ W1r,
                             const float* __restrict__ W2l,
                             const float* __restrict__ W2r,
                             ushort_t* __restrict__ W1t,
                             ushort_t* __restrict__ W2t) {
    int t = blockIdx.x * blockDim.x + threadIdx.x;
    if (t < 128 * F_IN) {
        int n = t / F_IN, k = t - n * F_IN;
        float v = (n < HID) ? W1l[k * HID + n] : W1r[k * HID + (n - HID)];
        W1t[t] = f2b(v);
    } else if (t < 128 * F_IN + 80 * HID) {
        int u = t - 128 * F_IN;
        int n = u / HID, k = u - n * HID;
        float v = (n < N_CLS) ? W2l[k * N_CLS + n] : W2r[k * N_CLS + (n - N_CLS)];
        W2t[u] = f2b(v);
    }
}

// ---------------------------------------------------------------------------
// gemm1_mfma: [y1b|z1b] = x @ [W1_l|W1_r]  via mfma_f32_16x16x32_bf16.
// ---------------------------------------------------------------------------
__global__ void gemm1_mfma_kernel(const float* __restrict__ x,
                                  const ushort_t* __restrict__ W1t,
                                  ushort_t* __restrict__ y1b,
                                  ushort_t* __restrict__ z1b) {
    int gid = blockIdx.x * blockDim.x + threadIdx.x;
    int wave = gid >> 6, lane = gid & 63;
    if (wave >= MT) return;
    int m0 = wave * 16;
    int r = lane & 15, q = lane >> 4;

    const float* xr = x + (size_t)(m0 + r) * F_IN + q * 8;
    bf8_t a[4];
#pragma unroll
    for (int kt = 0; kt < 4; ++kt) {
        float4 u = *(const float4*)(xr + kt * 32);
        float4 v = *(const float4*)(xr + kt * 32 + 4);
        bf8_t t;
        t[0] = (short)f2b(u.x); t[1] = (short)f2b(u.y);
        t[2] = (short)f2b(u.z); t[3] = (short)f2b(u.w);
        t[4] = (short)f2b(v.x); t[5] = (short)f2b(v.y);
        t[6] = (short)f2b(v.z); t[7] = (short)f2b(v.w);
        a[kt] = t;
    }
#pragma unroll
    for (int tn = 0; tn < 8; ++tn) {
        const ushort_t* wr = W1t + (size_t)(tn * 16 + r) * F_IN + q * 8;
        f4_t acc = {0.f, 0.f, 0.f, 0.f};
#pragma unroll
        for (int kt = 0; kt < 4; ++kt) {
            bf8_t b = *(const bf8_t*)(wr + kt * 32);
            acc = __builtin_amdgcn_mfma_f32_16x16x32_bf16(a[kt], b, acc, 0, 0, 0);
        }
        int col = tn * 16 + r;
        ushort_t* dst = (col < HID) ? (y1b + col) : (z1b + (col - HID));
#pragma unroll
        for (int rr = 0; rr < 4; ++rr) {
            int row = m0 + q * 4 + rr;
            dst[(size_t)row * HID] = f2b(acc[rr]);
        }
    }
}

// ---------------------------------------------------------------------------
// agg1 (+ fused epi): h = relu(mean y1[src] + b1 + z1)   [bf16 in, bf16 out]
// ---------------------------------------------------------------------------
__global__ void agg1_kernel(const int* __restrict__ rowptr,
                            const int* __restrict__ csr,
                            const ushort_t* __restrict__ y1b,
                            const ushort_t* __restrict__ z1b,
                            const float* __restrict__ b1,
                            ushort_t* __restrict__ hb) {
    int gid = blockIdx.x * blockDim.x + threadIdx.x;
    int n = gid >> 6;
    int j = gid & 63;
    if (n >= N_NODES) return;
    int beg = rowptr[n], end = rowptr[n + 1];
    float acc = 0.f;
    int i = beg;
    for (; i + 1 < end; i += 2) {
        int s0 = csr[i], s1 = csr[i + 1];
        float v0 = b2f(y1b[(size_t)s0 * HID + j]);
        float v1 = b2f(y1b[(size_t)s1 * HID + j]);
        acc += v0 + v1;
    }
    if (i < end) acc += b2f(y1b[(size_t)csr[i] * HID + j]);
    float inv = 1.0f / fmaxf((float)(end - beg), 1.0f);
    float v = fmaf(acc, inv, b1[j] + b2f(z1b[gid]));
    hb[gid] = f2b(fmaxf(v, 0.0f));
}

// ---------------------------------------------------------------------------
// gemm2_mfma: [y2b|z2b] = h @ [W2_l|W2_r]   K=64, N=80 (5 tiles of 16).
// ---------------------------------------------------------------------------
__global__ void gemm2_mfma_kernel(const ushort_t* __restrict__ hb,
                                  const ushort_t* __restrict__ W2t,
                                  ushort_t* __restrict__ y2b,
                                  ushort_t* __restrict__ z2b) {
    int gid = blockIdx.x * blockDim.x + threadIdx.x;
    int wave = gid >> 6, lane = gid & 63;
    if (wave >= MT) return;
    int m0 = wave * 16;
    int r = lane & 15, q = lane >> 4;

    const ushort_t* hr = hb + (size_t)(m0 + r) * HID + q * 8;
    bf8_t a[2];
#pragma unroll
    for (int kt = 0; kt < 2; ++kt)
        a[kt] = *(const bf8_t*)(hr + kt * 32);

#pragma unroll
    for (int tn = 0; tn < 5; ++tn) {
        const ushort_t* wr = W2t + (size_t)(tn * 16 + r) * HID + q * 8;
        f4_t acc = {0.f, 0.f, 0.f, 0.f};
#pragma unroll
        for (int kt = 0; kt < 2; ++kt) {
            bf8_t b = *(const bf8_t*)(wr + kt * 32);
            acc = __builtin_amdgcn_mfma_f32_16x16x32_bf16(a[kt], b, acc, 0, 0, 0);
        }
        int col = tn * 16 + r;
        ushort_t* dst = (col < N_CLS) ? (y2b + col) : (z2b + (col - N_CLS));
#pragma unroll
        for (int rr = 0; rr < 4; ++rr) {
            int row = m0 + q * 4 + rr;
            dst[(size_t)row * N_CLS] = f2b(acc[rr]);
        }
    }
}

// ---------------------------------------------------------------------------
// agg2 + log_softmax fused. One wave per dst node; lanes 0..39 = classes.
// ---------------------------------------------------------------------------
__global__ void agg2_kernel(const int* __restrict__ rowptr,
                            const int* __restrict__ csr,
                            const ushort_t* __restrict__ y2b,
                            const ushort_t* __restrict__ z2b,
                            const float* __restrict__ b2,
                            float* __restrict__ out) {
    int gid = blockIdx.x * blockDim.x + threadIdx.x;
    int n = gid >> 6;
    int j = gid & 63;
    if (n >= N_NODES) return;
    int jc = min(j, N_CLS - 1);
    int beg = rowptr[n], end = rowptr[n + 1];
    float acc = 0.f;
    int i = beg;
    for (; i + 1 < end; i += 2) {
        int s0 = csr[i], s1 = csr[i + 1];
        float v0 = b2f(y2b[(size_t)s0 * N_CLS + jc]);
        float v1 = b2f(y2b[(size_t)s1 * N_CLS + jc]);
        acc += v0 + v1;
    }
    if (i < end) acc += b2f(y2b[(size_t)csr[i] * N_CLS + jc]);

    float val = -INFINITY;
    if (j < N_CLS) {
        float inv = 1.0f / fmaxf((float)(end - beg), 1.0f);
        val = fmaf(acc, inv, b2[j] + b2f(z2b[(size_t)n * N_CLS + j]));
    }
    float m = val;
#pragma unroll
    for (int off = 32; off > 0; off >>= 1)
        m = fmaxf(m, __shfl_xor(m, off, 64));
    float ex = (j < N_CLS) ? expf(val - m) : 0.0f;
    float s = ex;
#pragma unroll
    for (int off = 32; off > 0; off >>= 1)
        s += __shfl_xor(s, off, 64);
    if (j < N_CLS) out[(size_t)n * N_CLS + j] = val - m - logf(s);
}

extern "C" void kernel_launch(void* const* d_in, const int* in_sizes, int n_in,
                              void* d_out, int out_size, void* d_ws, size_t ws_size,
                              hipStream_t stream) {
    const float* x   = (const float*)d_in[0];
    const int*   ei  = (const int*)d_in[1];
    const float* W1l = (const float*)d_in[2];
    const float* b1  = (const float*)d_in[3];
    const float* W1r = (const float*)d_in[4];
    const float* W2l = (const float*)d_in[5];
    const float* b2  = (const float*)d_in[6];
    const float* W2r = (const float*)d_in[7];
    float* out = (float*)d_out;
    const int E = in_sizes[1] / 2;
    const int nblk = (E + EPB - 1) / EPB;      // sort-pass blocks

    // Workspace layout (16B-aligned slices)
    char* p = (char*)d_ws;
    auto take = [&](size_t bytes) {
        char* q = p;
        p += (bytes + 15) & ~(size_t)15;
        return (void*)q;
    };
    int* rowptr     = (int*)take(sizeof(int) * (N_NODES + 4));
    int* blockHist  = (int*)take(sizeof(int) * (size_t)nblk * NB);
    int* blockBase  = (int*)take(sizeof(int) * (size_t)nblk * NB);
    int* btot       = (int*)take(sizeof(int) * NB);
    int* boff       = (int*)take(sizeof(int) * NB);
    int2* pairs     = (int2*)take(sizeof(int2) * (size_t)E);
    int* csr        = (int*)take(sizeof(int) * (size_t)E);
    ushort_t* W1t   = (ushort_t*)take(sizeof(ushort_t) * 128 * F_IN);
    ushort_t* W2t   = (ushort_t*)take(sizeof(ushort_t) * 80 * HID);
    ushort_t* y1b   = (ushort_t*)take(sizeof(ushort_t) * (size_t)N_NODES * HID);
    ushort_t* z1b   = (ushort_t*)take(sizeof(ushort_t) * (size_t)N_NODES * HID);
    ushort_t* hb    = (ushort_t*)take(sizeof(ushort_t) * (size_t)N_NODES * HID);
    ushort_t* y2b = y1b;   // y1b/z1b dead after agg1; N*40 < N*64
    ushort_t* z2b = z1b;

    const int B = 256;

    // CSR build: atomic-free two-level bucket sort
    block_hist_kernel<<<nblk, 256, 0, stream>>>(ei, E, blockHist);
    col_scan_kernel<<<NB, 256, 0, stream>>>(blockHist, nblk, blockBase, btot);
    bucket_scan_kernel<<<1, 256, 0, stream>>>(btot, boff, rowptr);
    scatter_pairs_kernel<<<nblk, 256, 0, stream>>>(ei, E, blockBase, boff, pairs);
    bucket_sort_kernel<<<NB, BSZ, 0, stream>>>(pairs, boff, btot, rowptr, csr);

    cvt_w_kernel<<<(128 * F_IN + 80 * HID + B - 1) / B, B, 0, stream>>>(
        W1l, W1r, W2l, W2r, W1t, W2t);

    int t_mfma = MT * 64;               // one wave per 16-node tile
    int t_nodes64 = N_NODES * 64;       // one wave per node

    gemm1_mfma_kernel<<<(t_mfma + B - 1) / B, B, 0, stream>>>(x, W1t, y1b, z1b);
    agg1_kernel<<<(t_nodes64 + B - 1) / B, B, 0, stream>>>(rowptr, csr, y1b, z1b, b1, hb);
    gemm2_mfma_kernel<<<(t_mfma + B - 1) / B, B, 0, stream>>>(hb, W2t, y2b, z2b);
    agg2_kernel<<<(t_nodes64 + B - 1) / B, B, 0, stream>>>(rowptr, csr, y2b, z2b, b2, out);
}

// Round 7
// 304.580 us; speedup vs baseline: 9.6203x; 1.3377x over previous
//
#include <hip/hip_runtime.h>
#include <math.h>

#define N_NODES 100000
#define F_IN    128
#define HID     64
#define N_CLS   40
#define MT      (N_NODES / 16)                  // 6250 M-tiles of 16 nodes

#define BSHIFT  9
#define BSZ     512                              // dsts per coarse bucket
#define NB      ((N_NODES + BSZ - 1) / BSZ)      // 196 buckets
#define EPB     4096                             // edges per block in sort passes

typedef __attribute__((ext_vector_type(8))) short bf8_t;   // 8 bf16 (4 VGPR)
typedef __attribute__((ext_vector_type(4))) float f4_t;    // MFMA C/D frag

typedef unsigned short ushort_t;
typedef unsigned int uint_t;

__device__ __forceinline__ ushort_t f2b(float f) {   // f32 -> bf16 RNE
    union { float f; uint_t u; } c; c.f = f;
    uint_t u = c.u + 0x7FFFu + ((c.u >> 16) & 1u);
    return (ushort_t)(u >> 16);
}
__device__ __forceinline__ float b2f(ushort_t h) {
    union { uint_t u; float f; } c; c.u = ((uint_t)h) << 16;
    return c.f;
}

// ---------------------------------------------------------------------------
// Sort pass 1: per-block LDS histogram over 196 coarse buckets (dst >> 9).
// ---------------------------------------------------------------------------
__global__ void block_hist_kernel(const int* __restrict__ ei, int E,
                                  int* __restrict__ blockHist) {
    __shared__ int cnt[NB];
    int t = threadIdx.x, blk = blockIdx.x;
    for (int i = t; i < NB; i += 256) cnt[i] = 0;
    __syncthreads();
    int e0 = blk * EPB;
#pragma unroll
    for (int i = 0; i < EPB / 256; ++i) {
        int e = e0 + i * 256 + t;
        if (e < E) atomicAdd(&cnt[ei[E + e] >> BSHIFT], 1);
    }
    __syncthreads();
    for (int i = t; i < NB; i += 256) blockHist[blk * NB + i] = cnt[i];
}

// ---------------------------------------------------------------------------
// Sort pass 2: per-bin exclusive scan down the blocks.
// ---------------------------------------------------------------------------
__global__ void col_scan_kernel(const int* __restrict__ blockHist, int nblk,
                                int* __restrict__ blockBase,
                                int* __restrict__ btot) {
    __shared__ int ss[256];
    __shared__ int carry;
    int bin = blockIdx.x, t = threadIdx.x;
    if (t == 0) carry = 0;
    __syncthreads();
    for (int c0 = 0; c0 < nblk; c0 += 256) {
        int b = c0 + t;
        int v = (b < nblk) ? blockHist[b * NB + bin] : 0;
        ss[t] = v;
        __syncthreads();
        for (int off = 1; off < 256; off <<= 1) {
            int u = (t >= off) ? ss[t - off] : 0;
            __syncthreads();
            ss[t] += u;
            __syncthreads();
        }
        if (b < nblk) blockBase[b * NB + bin] = carry + ss[t] - v;
        __syncthreads();
        if (t == 255) carry += ss[255];
        __syncthreads();
    }
    if (t == 0) btot[bin] = carry;
}

// ---------------------------------------------------------------------------
// Sort pass 3: exclusive scan over 196 bucket totals; rowptr[N] = E.
// ---------------------------------------------------------------------------
__global__ void bucket_scan_kernel(const int* __restrict__ btot,
                                   int* __restrict__ boff,
                                   int* __restrict__ rowptr) {
    __shared__ int ss[256];
    int t = threadIdx.x;
    int v = (t < NB) ? btot[t] : 0;
    ss[t] = v;
    __syncthreads();
    for (int off = 1; off < 256; off <<= 1) {
        int u = (t >= off) ? ss[t - off] : 0;
        __syncthreads();
        ss[t] += u;
        __syncthreads();
    }
    if (t < NB) boff[t] = ss[t] - v;
    if (t == NB - 1) rowptr[N_NODES] = ss[t];
}

// ---------------------------------------------------------------------------
// Sort pass 4: scatter packed (src<<9 | dst&511) into coarse-bucket order.
// ---------------------------------------------------------------------------
__global__ void scatter_pairs_kernel(const int* __restrict__ ei, int E,
                                     const int* __restrict__ blockBase,
                                     const int* __restrict__ boff,
                                     uint_t* __restrict__ pairs) {
    __shared__ int cur[NB];
    __shared__ int base[NB];
    int t = threadIdx.x, blk = blockIdx.x;
    for (int i = t; i < NB; i += 256) {
        cur[i] = 0;
        base[i] = boff[i] + blockBase[blk * NB + i];
    }
    __syncthreads();
    int e0 = blk * EPB;
#pragma unroll
    for (int i = 0; i < EPB / 256; ++i) {
        int e = e0 + i * 256 + t;
        if (e < E) {
            int src = ei[e];
            int dst = ei[E + e];
            int bin = dst >> BSHIFT;
            int r = atomicAdd(&cur[bin], 1);   // LDS atomic
            pairs[base[bin] + r] = ((uint_t)src << BSHIFT) | (uint_t)(dst & (BSZ - 1));
        }
    }
}

// ---------------------------------------------------------------------------
// Sort pass 5: per-bucket fine sort. rowptr + contiguous csr region.
// ---------------------------------------------------------------------------
__global__ void bucket_sort_kernel(const uint_t* __restrict__ pairs,
                                   const int* __restrict__ boff,
                                   const int* __restrict__ btot,
                                   int* __restrict__ rowptr,
                                   int* __restrict__ csr) {
    __shared__ int hist[BSZ];
    __shared__ int lofs[BSZ];
    int bin = blockIdx.x, t = threadIdx.x;
    int base = boff[bin], cnt = btot[bin];
    hist[t] = 0;
    __syncthreads();
    for (int i = t; i < cnt; i += BSZ)
        atomicAdd(&hist[pairs[base + i] & (BSZ - 1)], 1);
    __syncthreads();
    int v = hist[t];
    lofs[t] = v;
    __syncthreads();
    for (int off = 1; off < BSZ; off <<= 1) {
        int u = (t >= off) ? lofs[t - off] : 0;
        __syncthreads();
        lofs[t] += u;
        __syncthreads();
    }
    int excl = lofs[t] - v;
    int d_global = (bin << BSHIFT) + t;
    if (d_global < N_NODES) rowptr[d_global] = base + excl;
    __syncthreads();
    lofs[t] = excl;
    hist[t] = 0;
    __syncthreads();
    for (int i = t; i < cnt; i += BSZ) {
        uint_t p = pairs[base + i];
        int lb = p & (BSZ - 1);
        int r = atomicAdd(&hist[lb], 1);
        csr[base + lofs[lb] + r] = (int)(p >> BSHIFT);
    }
}

// ---------------------------------------------------------------------------
// cvt_w: bf16 [n][k]-major weight tensors.
// ---------------------------------------------------------------------------
__global__ void cvt_w_kernel(const float* __restrict__ W1l,
                             const float* __restrict__ W1r,
                             const float* __restrict__ W2l,
                             const float* __restrict__ W2r,
                             ushort_t* __restrict__ W1t,
                             ushort_t* __restrict__ W2t) {
    int t = blockIdx.x * blockDim.x + threadIdx.x;
    if (t < 128 * F_IN) {
        int n = t / F_IN, k = t - n * F_IN;
        float v = (n < HID) ? W1l[k * HID + n] : W1r[k * HID + (n - HID)];
        W1t[t] = f2b(v);
    } else if (t < 128 * F_IN + 80 * HID) {
        int u = t - 128 * F_IN;
        int n = u / HID, k = u - n * HID;
        float v = (n < N_CLS) ? W2l[k * N_CLS + n] : W2r[k * N_CLS + (n - N_CLS)];
        W2t[u] = f2b(v);
    }
}

// ---------------------------------------------------------------------------
// gemm1_mfma: [y1b|z1b] = x @ [W1_l|W1_r]  via mfma_f32_16x16x32_bf16.
// ---------------------------------------------------------------------------
__global__ void gemm1_mfma_kernel(const float* __restrict__ x,
                                  const ushort_t* __restrict__ W1t,
                                  ushort_t* __restrict__ y1b,
                                  ushort_t* __restrict__ z1b) {
    int gid = blockIdx.x * blockDim.x + threadIdx.x;
    int wave = gid >> 6, lane = gid & 63;
    if (wave >= MT) return;
    int m0 = wave * 16;
    int r = lane & 15, q = lane >> 4;

    const float* xr = x + (size_t)(m0 + r) * F_IN + q * 8;
    bf8_t a[4];
#pragma unroll
    for (int kt = 0; kt < 4; ++kt) {
        float4 u = *(const float4*)(xr + kt * 32);
        float4 v = *(const float4*)(xr + kt * 32 + 4);
        bf8_t t;
        t[0] = (short)f2b(u.x); t[1] = (short)f2b(u.y);
        t[2] = (short)f2b(u.z); t[3] = (short)f2b(u.w);
        t[4] = (short)f2b(v.x); t[5] = (short)f2b(v.y);
        t[6] = (short)f2b(v.z); t[7] = (short)f2b(v.w);
        a[kt] = t;
    }
#pragma unroll
    for (int tn = 0; tn < 8; ++tn) {
        const ushort_t* wr = W1t + (size_t)(tn * 16 + r) * F_IN + q * 8;
        f4_t acc = {0.f, 0.f, 0.f, 0.f};
#pragma unroll
        for (int kt = 0; kt < 4; ++kt) {
            bf8_t b = *(const bf8_t*)(wr + kt * 32);
            acc = __builtin_amdgcn_mfma_f32_16x16x32_bf16(a[kt], b, acc, 0, 0, 0);
        }
        int col = tn * 16 + r;
        ushort_t* dst = (col < HID) ? (y1b + col) : (z1b + (col - HID));
#pragma unroll
        for (int rr = 0; rr < 4; ++rr) {
            int row = m0 + q * 4 + rr;
            dst[(size_t)row * HID] = f2b(acc[rr]);
        }
    }
}

// ---------------------------------------------------------------------------
// agg1: h = relu(mean y1[src] + b1 + z1).  4 edge-groups of 16 lanes;
// each lane loads ushort4 (8B) -> one load instr fetches 4 edge rows (512B).
// Cross-group combine via shfl_xor(16|32).
// ---------------------------------------------------------------------------
__global__ void agg1_kernel(const int* __restrict__ rowptr,
                            const int* __restrict__ csr,
                            const ushort_t* __restrict__ y1b,
                            const ushort_t* __restrict__ z1b,
                            const float* __restrict__ b1,
                            ushort_t* __restrict__ hb) {
    int gid = blockIdx.x * blockDim.x + threadIdx.x;
    int n = gid >> 6;
    int lane = gid & 63;
    if (n >= N_NODES) return;
    int g = lane >> 4, l = lane & 15;
    int beg = rowptr[n], end = rowptr[n + 1];
    float a0 = 0.f, a1 = 0.f, a2 = 0.f, a3 = 0.f;
    int i = beg + g;
    for (; i + 4 < end; i += 8) {        // 2 rows in flight per group
        int s0 = csr[i], s1 = csr[i + 4];
        ushort4 v0 = *(const ushort4*)(y1b + (size_t)s0 * HID + l * 4);
        ushort4 v1 = *(const ushort4*)(y1b + (size_t)s1 * HID + l * 4);
        a0 += b2f(v0.x) + b2f(v1.x);
        a1 += b2f(v0.y) + b2f(v1.y);
        a2 += b2f(v0.z) + b2f(v1.z);
        a3 += b2f(v0.w) + b2f(v1.w);
    }
    if (i < end) {
        ushort4 v = *(const ushort4*)(y1b + (size_t)csr[i] * HID + l * 4);
        a0 += b2f(v.x); a1 += b2f(v.y); a2 += b2f(v.z); a3 += b2f(v.w);
    }
    a0 += __shfl_xor(a0, 16, 64); a0 += __shfl_xor(a0, 32, 64);
    a1 += __shfl_xor(a1, 16, 64); a1 += __shfl_xor(a1, 32, 64);
    a2 += __shfl_xor(a2, 16, 64); a2 += __shfl_xor(a2, 32, 64);
    a3 += __shfl_xor(a3, 16, 64); a3 += __shfl_xor(a3, 32, 64);

    if (g == 0) {
        float inv = 1.0f / fmaxf((float)(end - beg), 1.0f);
        float4 bb = *(const float4*)(b1 + l * 4);
        ushort4 zz = *(const ushort4*)(z1b + (size_t)n * HID + l * 4);
        float r0 = fmaxf(fmaf(a0, inv, bb.x + b2f(zz.x)), 0.f);
        float r1 = fmaxf(fmaf(a1, inv, bb.y + b2f(zz.y)), 0.f);
        float r2 = fmaxf(fmaf(a2, inv, bb.z + b2f(zz.z)), 0.f);
        float r3 = fmaxf(fmaf(a3, inv, bb.w + b2f(zz.w)), 0.f);
        ushort4 o;
        o.x = f2b(r0); o.y = f2b(r1); o.z = f2b(r2); o.w = f2b(r3);
        *(ushort4*)(hb + (size_t)n * HID + l * 4) = o;
    }
}

// ---------------------------------------------------------------------------
// gemm2_mfma: [y2b|z2b] = h @ [W2_l|W2_r], outputs PADDED to stride 64
// (cols 40..63 unused) so agg2 gets the same 4-group gather structure.
// ---------------------------------------------------------------------------
__global__ void gemm2_mfma_kernel(const ushort_t* __restrict__ hb,
                                  const ushort_t* __restrict__ W2t,
                                  ushort_t* __restrict__ y2b,
                                  ushort_t* __restrict__ z2b) {
    int gid = blockIdx.x * blockDim.x + threadIdx.x;
    int wave = gid >> 6, lane = gid & 63;
    if (wave >= MT) return;
    int m0 = wave * 16;
    int r = lane & 15, q = lane >> 4;

    const ushort_t* hr = hb + (size_t)(m0 + r) * HID + q * 8;
    bf8_t a[2];
#pragma unroll
    for (int kt = 0; kt < 2; ++kt)
        a[kt] = *(const bf8_t*)(hr + kt * 32);

#pragma unroll
    for (int tn = 0; tn < 5; ++tn) {
        const ushort_t* wr = W2t + (size_t)(tn * 16 + r) * HID + q * 8;
        f4_t acc = {0.f, 0.f, 0.f, 0.f};
#pragma unroll
        for (int kt = 0; kt < 2; ++kt) {
            bf8_t b = *(const bf8_t*)(wr + kt * 32);
            acc = __builtin_amdgcn_mfma_f32_16x16x32_bf16(a[kt], b, acc, 0, 0, 0);
        }
        int col = tn * 16 + r;
        ushort_t* dst = (col < N_CLS) ? (y2b + col) : (z2b + (col - N_CLS));
#pragma unroll
        for (int rr = 0; rr < 4; ++rr) {
            int row = m0 + q * 4 + rr;
            dst[(size_t)row * HID] = f2b(acc[rr]);   // stride 64 (padded)
        }
    }
}

// ---------------------------------------------------------------------------
// agg2 + log_softmax. Same 4-group structure; pad cols (>=40) masked to -inf
// before the softmax reductions. Output f32 [N,40].
// ---------------------------------------------------------------------------
__global__ void agg2_kernel(const int* __restrict__ rowptr,
                            const int* __restrict__ csr,
                            const ushort_t* __restrict__ y2b,
                            const ushort_t* __restrict__ z2b,
                            const float* __restrict__ b2,
                            float* __restrict__ out) {
    int gid = blockIdx.x * blockDim.x + threadIdx.x;
    int n = gid >> 6;
    int lane = gid & 63;
    if (n >= N_NODES) return;
    int g = lane >> 4, l = lane & 15;
    int beg = rowptr[n], end = rowptr[n + 1];
    float a0 = 0.f, a1 = 0.f, a2 = 0.f, a3 = 0.f;
    int i = beg + g;
    for (; i + 4 < end; i += 8) {
        int s0 = csr[i], s1 = csr[i + 4];
        ushort4 v0 = *(const ushort4*)(y2b + (size_t)s0 * HID + l * 4);
        ushort4 v1 = *(const ushort4*)(y2b + (size_t)s1 * HID + l * 4);
        a0 += b2f(v0.x) + b2f(v1.x);
        a1 += b2f(v0.y) + b2f(v1.y);
        a2 += b2f(v0.z) + b2f(v1.z);
        a3 += b2f(v0.w) + b2f(v1.w);
    }
    if (i < end) {
        ushort4 v = *(const ushort4*)(y2b + (size_t)csr[i] * HID + l * 4);
        a0 += b2f(v.x); a1 += b2f(v.y); a2 += b2f(v.z); a3 += b2f(v.w);
    }
    a0 += __shfl_xor(a0, 16, 64); a0 += __shfl_xor(a0, 32, 64);
    a1 += __shfl_xor(a1, 16, 64); a1 += __shfl_xor(a1, 32, 64);
    a2 += __shfl_xor(a2, 16, 64); a2 += __shfl_xor(a2, 32, 64);
    a3 += __shfl_xor(a3, 16, 64); a3 += __shfl_xor(a3, 32, 64);

    float inv = 1.0f / fmaxf((float)(end - beg), 1.0f);
    int c0 = l * 4;
    float4 bb = (l < 10) ? *(const float4*)(b2 + c0)
                         : make_float4(0.f, 0.f, 0.f, 0.f);
    ushort4 zz = *(const ushort4*)(z2b + (size_t)n * HID + c0);
    float v0 = (c0 + 0 < N_CLS) ? fmaf(a0, inv, bb.x + b2f(zz.x)) : -INFINITY;
    float v1 = (c0 + 1 < N_CLS) ? fmaf(a1, inv, bb.y + b2f(zz.y)) : -INFINITY;
    float v2 = (c0 + 2 < N_CLS) ? fmaf(a2, inv, bb.z + b2f(zz.z)) : -INFINITY;
    float v3 = (c0 + 3 < N_CLS) ? fmaf(a3, inv, bb.w + b2f(zz.w)) : -INFINITY;

    float m = fmaxf(fmaxf(v0, v1), fmaxf(v2, v3));
#pragma unroll
    for (int off = 1; off < 16; off <<= 1)
        m = fmaxf(m, __shfl_xor(m, off, 64));
    float s = 0.f;
    if (v0 > -INFINITY) s += expf(v0 - m);
    if (v1 > -INFINITY) s += expf(v1 - m);
    if (v2 > -INFINITY) s += expf(v2 - m);
    if (v3 > -INFINITY) s += expf(v3 - m);
#pragma unroll
    for (int off = 1; off < 16; off <<= 1)
        s += __shfl_xor(s, off, 64);
    float ls = logf(s);
    if (g == 0 && l < 10) {
        float4 o = make_float4(v0 - m - ls, v1 - m - ls, v2 - m - ls, v3 - m - ls);
        *(float4*)(out + (size_t)n * N_CLS + c0) = o;
    }
}

extern "C" void kernel_launch(void* const* d_in, const int* in_sizes, int n_in,
                              void* d_out, int out_size, void* d_ws, size_t ws_size,
                              hipStream_t stream) {
    const float* x   = (const float*)d_in[0];
    const int*   ei  = (const int*)d_in[1];
    const float* W1l = (const float*)d_in[2];
    const float* b1  = (const float*)d_in[3];
    const float* W1r = (const float*)d_in[4];
    const float* W2l = (const float*)d_in[5];
    const float* b2  = (const float*)d_in[6];
    const float* W2r = (const float*)d_in[7];
    float* out = (float*)d_out;
    const int E = in_sizes[1] / 2;
    const int nblk = (E + EPB - 1) / EPB;

    char* p = (char*)d_ws;
    auto take = [&](size_t bytes) {
        char* q = p;
        p += (bytes + 15) & ~(size_t)15;
        return (void*)q;
    };
    int* rowptr     = (int*)take(sizeof(int) * (N_NODES + 4));
    int* blockHist  = (int*)take(sizeof(int) * (size_t)nblk * NB);
    int* blockBase  = (int*)take(sizeof(int) * (size_t)nblk * NB);
    int* btot       = (int*)take(sizeof(int) * NB);
    int* boff       = (int*)take(sizeof(int) * NB);
    uint_t* pairs   = (uint_t*)take(sizeof(uint_t) * (size_t)E);
    int* csr        = (int*)take(sizeof(int) * (size_t)E);
    ushort_t* W1t   = (ushort_t*)take(sizeof(ushort_t) * 128 * F_IN);
    ushort_t* W2t   = (ushort_t*)take(sizeof(ushort_t) * 80 * HID);
    ushort_t* y1b   = (ushort_t*)take(sizeof(ushort_t) * (size_t)N_NODES * HID);
    ushort_t* z1b   = (ushort_t*)take(sizeof(ushort_t) * (size_t)N_NODES * HID);
    ushort_t* hb    = (ushort_t*)take(sizeof(ushort_t) * (size_t)N_NODES * HID);
    ushort_t* y2b = y1b;   // stride-64 padded; y1b/z1b dead after agg1
    ushort_t* z2b = z1b;

    const int B = 256;

    block_hist_kernel<<<nblk, 256, 0, stream>>>(ei, E, blockHist);
    col_scan_kernel<<<NB, 256, 0, stream>>>(blockHist, nblk, blockBase, btot);
    bucket_scan_kernel<<<1, 256, 0, stream>>>(btot, boff, rowptr);
    scatter_pairs_kernel<<<nblk, 256, 0, stream>>>(ei, E, blockBase, boff, pairs);
    bucket_sort_kernel<<<NB, BSZ, 0, stream>>>(pairs, boff, btot, rowptr, csr);

    cvt_w_kernel<<<(128 * F_IN + 80 * HID + B - 1) / B, B, 0, stream>>>(
        W1l, W1r, W2l, W2r, W1t, W2t);

    int t_mfma = MT * 64;
    int t_nodes64 = N_NODES * 64;

    gemm1_mfma_kernel<<<(t_mfma + B - 1) / B, B, 0, stream>>>(x, W1t, y1b, z1b);
    agg1_kernel<<<(t_nodes64 + B - 1) / B, B, 0, stream>>>(rowptr, csr, y1b, z1b, b1, hb);
    gemm2_mfma_kernel<<<(t_mfma + B - 1) / B, B, 0, stream>>>(hb, W2t, y2b, z2b);
    agg2_kernel<<<(t_nodes64 + B - 1) / B, B, 0, stream>>>(rowptr, csr, y2b, z2b, b2, out);
}